// Round 4
// baseline (1151.401 us; speedup 1.0000x reference)
//
#include <hip/hip_runtime.h>
#include <hip/hip_bf16.h>

typedef __hip_bfloat16 bf16;
using bf16x8 = __attribute__((ext_vector_type(8))) __bf16;
using f32x4  = __attribute__((ext_vector_type(4))) float;

#define S_   2048
#define D_   2048
#define H_   16
#define QR_  1536
#define KVR_ 512
#define NOPE_ 128
#define ROPE_ 64
#define VD_  128
#define QKD_ 192
#define EPS_ 1e-5f
#define QKVN 2112   // QR_ + KVR_ + ROPE_ (fused qa+kva output width)

// async global->LDS, 16B per lane; LDS dest = wave-uniform base + lane*16
#define GLDS16(g, l) \
    __builtin_amdgcn_global_load_lds((const __attribute__((address_space(1))) void*)(g), \
                                     (__attribute__((address_space(3))) void*)(l), 16, 0, 0)

#define PIPE_WAIT4 asm volatile("s_waitcnt vmcnt(4)\n\ts_barrier" ::: "memory")
#define PIPE_WAIT0 asm volatile("s_waitcnt vmcnt(0)\n\ts_barrier" ::: "memory")

// ---------------------------------------------------------------------------
// bf16 MFMA GEMM (128x128 tile, 4 waves) — retained for causal scores / PV /
// small-K kv_b. 3-stage pipelined, vmcnt(4) barriers.
// mode: 0=f32, 1=bf16, 2=f32+res, 3=bf16 gelu(x+bias), 4=f32+bias+res, 6=f32 partial
// causal: 0 none, 1 skip upper tiles, 2 K limited to diagonal
// ---------------------------------------------------------------------------
__global__ __launch_bounds__(256) void gemm_k(
    const bf16* __restrict__ A, const bf16* __restrict__ BT, void* __restrict__ Cv,
    const float* __restrict__ bias, const float* __restrict__ res,
    int M, int N, int K, int lda, int ldb, int ldc,
    long long strideA, long long strideB, long long strideC,
    int mode, int causal, int ksplit, int kchunk)
{
    int bn = blockIdx.x, bm = blockIdx.y;
    int bzC = blockIdx.z;
    int bz = bzC, kc = 0;
    if (ksplit > 1) { kc = bzC % ksplit; bz = bzC / ksplit; }
    if (causal == 1 && bn > bm) return;
    A  += (size_t)bz * strideA;
    BT += (size_t)bz * strideB;

    int k_end = K;
    if (causal == 2) { int kl = (bm + 1) * 128; if (kl < k_end) k_end = kl; }
    int k_begin = kc * kchunk;
    if (k_begin + kchunk < k_end) k_end = k_begin + kchunk;
    if (k_begin >= k_end) return;
    int nIter = (k_end - k_begin) >> 5;

    __shared__ bf16 sA[3 * 128 * 32];
    __shared__ bf16 sB[3 * 128 * 32];

    int tid  = threadIdx.x;
    int lane = tid & 63, wave = tid >> 6;
    int wr = wave >> 1, wc = wave & 1;
    int fr = lane & 15, fq = lane >> 4;

    int row0 = bm * 128, col0 = bn * 128;

    int srow = wave * 16 + (lane >> 2);
    int sko  = (lane & 3) * 8;
    const bf16* ga0 = A + (size_t)(row0 + srow) * lda + sko;
    const bf16* ga1 = ga0 + (size_t)64 * lda;
    int bn0 = col0 + srow;      if (bn0 > N - 1) bn0 = N - 1;
    int bn1 = col0 + srow + 64; if (bn1 > N - 1) bn1 = N - 1;
    const bf16* gb0 = BT + (size_t)bn0 * ldb + sko;
    const bf16* gb1 = BT + (size_t)bn1 * ldb + sko;
    bf16* lA0 = &sA[(wave * 16) * 32];
    bf16* lA1 = &sA[(64 + wave * 16) * 32];
    bf16* lB0 = &sB[(wave * 16) * 32];
    bf16* lB1 = &sB[(64 + wave * 16) * 32];

#define STAGE(ofs, k0) do {                  \
        GLDS16(ga0 + (k0), lA0 + (ofs));     \
        GLDS16(ga1 + (k0), lA1 + (ofs));     \
        GLDS16(gb0 + (k0), lB0 + (ofs));     \
        GLDS16(gb1 + (k0), lB1 + (ofs));     \
    } while (0)

    f32x4 acc[4][4] = {};

#define COMPUTE(ofs) do {                                                           \
        bf16x8 af[4], bv[4];                                                        \
        _Pragma("unroll")                                                           \
        for (int i = 0; i < 4; ++i)                                                 \
            af[i] = *(const bf16x8*)&sA[(ofs) + (wr*64 + i*16 + fr)*32 + fq*8];     \
        _Pragma("unroll")                                                           \
        for (int j = 0; j < 4; ++j)                                                 \
            bv[j] = *(const bf16x8*)&sB[(ofs) + (wc*64 + j*16 + fr)*32 + fq*8];     \
        _Pragma("unroll")                                                           \
        for (int i = 0; i < 4; ++i)                                                 \
            _Pragma("unroll")                                                       \
            for (int j = 0; j < 4; ++j)                                             \
                acc[i][j] = __builtin_amdgcn_mfma_f32_16x16x32_bf16(af[i], bv[j], acc[i][j], 0, 0, 0); \
    } while (0)

    STAGE(0, k_begin);
    if (nIter > 1) STAGE(4096, k_begin + 32);

    int curo = 0, pfo = 8192;
    int it = 0;
    for (; it < nIter - 1; ++it) {
        PIPE_WAIT4;
        if (it + 2 < nIter) STAGE(pfo, k_begin + (it + 2) * 32);
        COMPUTE(curo);
        curo += 4096; if (curo == 12288) curo = 0;
        pfo  += 4096; if (pfo  == 12288) pfo  = 0;
    }
    PIPE_WAIT0;
    COMPUTE(curo);
#undef STAGE
#undef COMPUTE

    #pragma unroll
    for (int i = 0; i < 4; ++i) {
        #pragma unroll
        for (int j = 0; j < 4; ++j) {
            int gc = col0 + wc*64 + j*16 + fr;
            if (gc >= N) continue;
            #pragma unroll
            for (int r = 0; r < 4; ++r) {
                int gr = row0 + wr*64 + i*16 + fq*4 + r;
                float v = acc[i][j][r];
                size_t off = (size_t)bzC * strideC + (size_t)gr * ldc + gc;
                if (mode == 0 || mode == 6) {
                    ((float*)Cv)[off] = v;
                } else if (mode == 1) {
                    ((bf16*)Cv)[off] = __float2bfloat16(v);
                } else if (mode == 2) {
                    ((float*)Cv)[off] = v + res[(size_t)gr * ldc + gc];
                } else if (mode == 3) {
                    float t = v + bias[gc];
                    t = 0.5f * t * (1.0f + erff(t * 0.70710678118654752f));
                    ((bf16*)Cv)[off] = __float2bfloat16(t);
                } else {
                    ((float*)Cv)[off] = v + bias[gc] + res[(size_t)gr * ldc + gc];
                }
            }
        }
    }
}

// ---------------------------------------------------------------------------
// 256x256-tile, 8-wave, 8-phase bf16 GEMM with ONE-PHASE-AHEAD register reads
// and COUNTED lgkm gates (T4 applied to the DS queue, m218 lineage).
//  - BK=64, double-buffered LDS (128 KiB); chunk-XOR swizzle (0 bank conflicts).
//  - Each phase's MFMA consumes fragments read in an EARLIER phase; the lgkm
//    gate waits only for those older reads (counted N = reads just issued),
//    so each phase's ds_read burst executes concurrently with its MFMA burst.
//      ph1: read B-hi(t) [4];  stage A1(t+1); gate lgkm(4);  MFMA lo x lo
//      ph2: read A-hi(t) [8];  stage B0(t+2); gate lgkm(8);  MFMA lo x hi
//      ph3: (no reads);        stage B1(t+2); gate lgkm(0);  MFMA hi x lo
//      ph4: stage A0(t+2); vmcnt(6); barrier;
//           read A-lo,B-lo(t+1) [12, ungated]; MFMA hi x hi
//    ph4's reads are safe: the vmcnt(6)+barrier guarantees tile t+1 resident
//    block-wide; in-flight DMA all targets the CURRENT buffer (disjoint).
//  - vmcnt(6) once per K-tile (3 half-tiles of t+2 stay in flight).
// mode: 0=f32, 1=bf16, 3=bf16 gelu(x+bias), 6=f32 partial (plane = blockIdx.z)
// Requires M%256==0; N edge handled by clamp+store-guard; K chunk %64==0.
// ---------------------------------------------------------------------------
__global__ __launch_bounds__(512, 2) void gemm256_k(
    const bf16* __restrict__ A, const bf16* __restrict__ BT, void* __restrict__ Cv,
    const float* __restrict__ bias,
    int M, int N, int K, int lda, int ldb, int ldc,
    long long strideC, int mode, int kchunk)
{
    int bn = blockIdx.x, bm = blockIdx.y, kc = blockIdx.z;
    int k_begin = kc * kchunk;
    int k_end = (k_begin + kchunk < K) ? (k_begin + kchunk) : K;
    int NT = (k_end - k_begin) >> 6;

    __shared__ __align__(16) bf16 sA[2 * 256 * 64];   // 64 KiB
    __shared__ __align__(16) bf16 sB[2 * 256 * 64];   // 64 KiB

    int tid = threadIdx.x;
    int lane = tid & 63, w = tid >> 6;
    int wr = w >> 2, wc = w & 3;            // 2x4 wave grid; wave owns 128x64
    int fr = lane & 15, fq = lane >> 4;
    int row0 = bm * 256, col0 = bn * 256;

    // staging: chunk g in [0,1024) covers half-tile 128rows x 64cols; thread
    // owns g=tid and g=tid+512. phys chunk p=g&7 holds logical l=p^(row&7).
    int g0 = tid, g1 = tid + 512;
    int r0 = g0 >> 3, l0 = (g0 & 7) ^ (r0 & 7);
    int r1 = g1 >> 3, l1 = (g1 & 7) ^ (r1 & 7);
    const bf16* gA00 = A + (size_t)(row0 + r0) * lda + k_begin + l0 * 8;
    const bf16* gA01 = A + (size_t)(row0 + r1) * lda + k_begin + l1 * 8;
    const bf16* gA10 = gA00 + (size_t)128 * lda;
    const bf16* gA11 = gA01 + (size_t)128 * lda;
    int c00 = col0 + r0;       if (c00 > N - 1) c00 = N - 1;
    int c01 = col0 + r1;       if (c01 > N - 1) c01 = N - 1;
    int c10 = col0 + 128 + r0; if (c10 > N - 1) c10 = N - 1;
    int c11 = col0 + 128 + r1; if (c11 > N - 1) c11 = N - 1;
    const bf16* gB00 = BT + (size_t)c00 * ldb + k_begin + l0 * 8;
    const bf16* gB01 = BT + (size_t)c01 * ldb + k_begin + l1 * 8;
    const bf16* gB10 = BT + (size_t)c10 * ldb + k_begin + l0 * 8;
    const bf16* gB11 = BT + (size_t)c11 * ldb + k_begin + l1 * 8;

#define ST_HALF(arr, bofs, p0, p1, t) do {                                  \
        GLDS16((p0) + (size_t)(t) * 64, (arr) + (bofs) + w * 512);          \
        GLDS16((p1) + (size_t)(t) * 64, (arr) + (bofs) + w * 512 + 4096);   \
    } while (0)
#define ST_A0(b, t) ST_HALF(sA, (b) * 16384,        gA00, gA01, t)
#define ST_A1(b, t) ST_HALF(sA, (b) * 16384 + 8192, gA10, gA11, t)
#define ST_B0(b, t) ST_HALF(sB, (b) * 16384,        gB00, gB01, t)
#define ST_B1(b, t) ST_HALF(sB, (b) * 16384 + 8192, gB10, gB11, t)

    // ds_read addressing (elements): row*64 + ((ksub*4+fq)^(fr&7))*8
    int arow = (wr * 128 + fr) * 64;
    int brow = (wc * 64 + fr) * 64;
    int pk0 = (fq ^ (fr & 7)) * 8;
    int pk1 = pk0 ^ 32;    // ksub=1: ((fq^4)^(fr&7))*8

    f32x4 acc[8][4] = {};

    // quadrant MFMA: 8 independent k0 MFMAs, then their 8 k1 partners
#define MFMA_Q(AF, BF, IOFF, JOFF) do {                                     \
        __builtin_amdgcn_s_setprio(1);                                      \
        _Pragma("unroll")                                                   \
        for (int m = 0; m < 4; ++m)                                         \
            _Pragma("unroll")                                               \
            for (int n = 0; n < 2; ++n)                                     \
                acc[(IOFF)+m][(JOFF)+n] = __builtin_amdgcn_mfma_f32_16x16x32_bf16( \
                    AF[m][0], BF[n][0], acc[(IOFF)+m][(JOFF)+n], 0, 0, 0);  \
        _Pragma("unroll")                                                   \
        for (int m = 0; m < 4; ++m)                                         \
            _Pragma("unroll")                                               \
            for (int n = 0; n < 2; ++n)                                     \
                acc[(IOFF)+m][(JOFF)+n] = __builtin_amdgcn_mfma_f32_16x16x32_bf16( \
                    AF[m][1], BF[n][1], acc[(IOFF)+m][(JOFF)+n], 0, 0, 0);  \
        __builtin_amdgcn_s_setprio(0);                                      \
    } while (0)

    // prologue: tile0 fully + 3 halves of tile1; force tile0 landed
    ST_A0(0, 0); ST_A1(0, 0); ST_B0(0, 0); ST_B1(0, 0);
    if (NT > 1) { ST_B0(1, 1); ST_B1(1, 1); ST_A0(1, 1); }
    if (NT > 1) asm volatile("s_waitcnt vmcnt(6)" ::: "memory");
    else        asm volatile("s_waitcnt vmcnt(0)" ::: "memory");
    __builtin_amdgcn_s_barrier();

    bf16x8 a_lo[4][2], a_hi[4][2], b_lo[2][2], b_hi[2][2];
    // pre-read A-lo, B-lo of tile 0 (buf 0); consumed at ph1 after lgkm(4)
    #pragma unroll
    for (int m = 0; m < 4; ++m) {
        a_lo[m][0] = *(const bf16x8*)&sA[arow + m*1024 + pk0];
        a_lo[m][1] = *(const bf16x8*)&sA[arow + m*1024 + pk1];
    }
    #pragma unroll
    for (int n = 0; n < 2; ++n) {
        b_lo[n][0] = *(const bf16x8*)&sB[brow + n*1024 + pk0];
        b_lo[n][1] = *(const bf16x8*)&sB[brow + n*1024 + pk1];
    }

    for (int t = 0; t < NT; ++t) {
        int buf = t & 1;
        int sbase = buf * 16384;
        int nbase = sbase ^ 16384;

        // ---- ph1: read B-hi(t); stage A1(t+1); gate lgkm(4); MFMA lo x lo
        #pragma unroll
        for (int n = 0; n < 2; ++n) {
            b_hi[n][0] = *(const bf16x8*)&sB[sbase + brow + (n+2)*1024 + pk0];
            b_hi[n][1] = *(const bf16x8*)&sB[sbase + brow + (n+2)*1024 + pk1];
        }
        if (t + 1 < NT) ST_A1((t + 1) & 1, t + 1);
        __builtin_amdgcn_sched_barrier(0);
        __builtin_amdgcn_s_barrier();
        asm volatile("s_waitcnt lgkmcnt(4)" ::: "memory");
        __builtin_amdgcn_sched_barrier(0);
        MFMA_Q(a_lo, b_lo, 0, 0);
        __builtin_amdgcn_s_barrier();

        // ---- ph2: read A-hi(t); stage B0(t+2); gate lgkm(8); MFMA lo x hi
        #pragma unroll
        for (int m = 0; m < 4; ++m) {
            a_hi[m][0] = *(const bf16x8*)&sA[sbase + arow + 4096 + m*1024 + pk0];
            a_hi[m][1] = *(const bf16x8*)&sA[sbase + arow + 4096 + m*1024 + pk1];
        }
        if (t + 2 < NT) ST_B0(buf, t + 2);
        __builtin_amdgcn_sched_barrier(0);
        __builtin_amdgcn_s_barrier();
        asm volatile("s_waitcnt lgkmcnt(8)" ::: "memory");
        __builtin_amdgcn_sched_barrier(0);
        MFMA_Q(a_lo, b_hi, 0, 2);
        __builtin_amdgcn_s_barrier();

        // ---- ph3: stage B1(t+2); gate lgkm(0); MFMA hi x lo
        if (t + 2 < NT) ST_B1(buf, t + 2);
        __builtin_amdgcn_sched_barrier(0);
        __builtin_amdgcn_s_barrier();
        asm volatile("s_waitcnt lgkmcnt(0)" ::: "memory");
        __builtin_amdgcn_sched_barrier(0);
        MFMA_Q(a_hi, b_lo, 4, 0);
        __builtin_amdgcn_s_barrier();

        // ---- ph4: stage A0(t+2); vmcnt; barrier; read A-lo,B-lo(t+1) ungated;
        //           MFMA hi x hi (operands already landed at ph3 gate)
        if (t + 2 < NT) ST_A0(buf, t + 2);
        if (t < NT - 2) asm volatile("s_waitcnt vmcnt(6)" ::: "memory");
        else            asm volatile("s_waitcnt vmcnt(0)" ::: "memory");
        __builtin_amdgcn_s_barrier();
        if (t + 1 < NT) {
            #pragma unroll
            for (int m = 0; m < 4; ++m) {
                a_lo[m][0] = *(const bf16x8*)&sA[nbase + arow + m*1024 + pk0];
                a_lo[m][1] = *(const bf16x8*)&sA[nbase + arow + m*1024 + pk1];
            }
            #pragma unroll
            for (int n = 0; n < 2; ++n) {
                b_lo[n][0] = *(const bf16x8*)&sB[nbase + brow + n*1024 + pk0];
                b_lo[n][1] = *(const bf16x8*)&sB[nbase + brow + n*1024 + pk1];
            }
        }
        __builtin_amdgcn_sched_barrier(0);
        MFMA_Q(a_hi, b_hi, 4, 2);
        __builtin_amdgcn_s_barrier();
    }
#undef MFMA_Q
#undef ST_A0
#undef ST_A1
#undef ST_B0
#undef ST_B1
#undef ST_HALF

    // epilogue: D[row = i*16 + fq*4 + r][col = j*16 + fr] (m89 layout)
    #pragma unroll
    for (int i = 0; i < 8; ++i) {
        #pragma unroll
        for (int j = 0; j < 4; ++j) {
            int gc = col0 + wc*64 + j*16 + fr;
            if (gc >= N) continue;
            #pragma unroll
            for (int r = 0; r < 4; ++r) {
                int gr = row0 + wr*128 + i*16 + fq*4 + r;
                float v = acc[i][j][r];
                size_t off = (size_t)kc * strideC + (size_t)gr * ldc + gc;
                if (mode == 0 || mode == 6) {
                    ((float*)Cv)[off] = v;
                } else if (mode == 1) {
                    ((bf16*)Cv)[off] = __float2bfloat16(v);
                } else {  // mode 3: gelu(x + bias) -> bf16
                    float tt = v + bias[gc];
                    tt = 0.5f * tt * (1.0f + erff(tt * 0.70710678118654752f));
                    ((bf16*)Cv)[off] = __float2bfloat16(tt);
                }
            }
        }
    }
}

// ---------------------------------------------------------------------------
// Split-K reduce: dst = sum of nch partial planes (+res)(+bias), float4.
// ---------------------------------------------------------------------------
__global__ __launch_bounds__(256) void red_k(const float* __restrict__ part,
        long long pstride4, int nch, const float* __restrict__ res,
        const float* __restrict__ bias, long long cols4,
        float* __restrict__ dstF, bf16* __restrict__ dstB, long long n4)
{
    long long i = (long long)blockIdx.x * 256 + threadIdx.x;
    long long stride = (long long)gridDim.x * 256;
    for (; i < n4; i += stride) {
        float4 v = ((const float4*)part)[i];
        for (int k = 1; k < nch; ++k) {
            float4 p = ((const float4*)part)[i + k * pstride4];
            v.x += p.x; v.y += p.y; v.z += p.z; v.w += p.w;
        }
        if (res) {
            float4 rr = ((const float4*)res)[i];
            v.x += rr.x; v.y += rr.y; v.z += rr.z; v.w += rr.w;
        }
        if (bias) {
            float4 b = ((const float4*)bias)[i % cols4];
            v.x += b.x; v.y += b.y; v.z += b.z; v.w += b.w;
        }
        if (dstB) {
            ushort4 o;
            bf16 t0 = __float2bfloat16(v.x); o.x = *(unsigned short*)&t0;
            bf16 t1 = __float2bfloat16(v.y); o.y = *(unsigned short*)&t1;
            bf16 t2 = __float2bfloat16(v.z); o.z = *(unsigned short*)&t2;
            bf16 t3 = __float2bfloat16(v.w); o.w = *(unsigned short*)&t3;
            ((ushort4*)dstB)[i] = o;
        } else {
            ((float4*)dstF)[i] = v;
        }
    }
}

// PV split-K reduce with causal chunk-validity: part[head][4][S][128] (kchunk=512)
__global__ __launch_bounds__(128) void pv_red(const float* __restrict__ part,
                                              bf16* __restrict__ ao, int grp)
{
    int r = blockIdx.x, head = blockIdx.y, d = threadIdx.x;
    int nv = ((r >> 7) + 4) >> 2;
    const float* p = part + ((size_t)head * 4) * S_ * VD_ + (size_t)r * VD_ + d;
    float s = 0.f;
    for (int k = 0; k < nv; ++k) s += p[(size_t)k * S_ * VD_];
    ao[(size_t)r * (H_ * VD_) + grp * 1024 + head * VD_ + d] = __float2bfloat16(s);
}

// ---------------------------------------------------------------------------
// Weight transpose + f32->bf16:  in[R,C] f32  ->  out[C,R] bf16
// ---------------------------------------------------------------------------
__global__ __launch_bounds__(256) void transpose_w(const float* __restrict__ in,
                                                   bf16* __restrict__ out, int R, int C)
{
    __shared__ float t[32][33];
    int c0 = blockIdx.x * 32, r0 = blockIdx.y * 32;
    int tx = threadIdx.x, ty = threadIdx.y;
    for (int j = ty; j < 32; j += 8) {
        int r = r0 + j, c = c0 + tx;
        t[j][tx] = (r < R && c < C) ? in[(size_t)r * C + c] : 0.f;
    }
    __syncthreads();
    for (int j = ty; j < 32; j += 8) {
        int c = c0 + j, r = r0 + tx;
        if (c < C && r < R) out[(size_t)c * R + r] = __float2bfloat16(t[tx][j]);
    }
}

// vT[h][d][s] = kv[s][h*256 + 128 + d]
__global__ __launch_bounds__(256) void transpose_v(const bf16* __restrict__ kv,
                                                   bf16* __restrict__ vT)
{
    __shared__ bf16 t[32][33];
    int h = blockIdx.z;
    int d0 = blockIdx.x * 32, s0 = blockIdx.y * 32;
    int tx = threadIdx.x, ty = threadIdx.y;
    for (int j = ty; j < 32; j += 8)
        t[j][tx] = kv[(size_t)(s0 + j) * (H_*256) + h*256 + 128 + d0 + tx];
    __syncthreads();
    for (int j = ty; j < 32; j += 8)
        vT[((size_t)h * VD_ + d0 + j) * S_ + s0 + tx] = t[tx][j];
}

// ---------------------------------------------------------------------------
// RMSNorm: f32 in (strided) -> bf16 out
// ---------------------------------------------------------------------------
__global__ __launch_bounds__(256) void rmsnorm_k(const float* __restrict__ in,
                                                 const float* __restrict__ w,
                                                 bf16* __restrict__ out,
                                                 int cols, int istride, int ostride)
{
    int row = blockIdx.x, tid = threadIdx.x;
    const float* ip = in + (size_t)row * istride;
    bf16* op = out + (size_t)row * ostride;
    float ss = 0.f;
    for (int c = tid; c < cols; c += 256) { float v = ip[c]; ss = fmaf(v, v, ss); }
    for (int o = 32; o > 0; o >>= 1) ss += __shfl_down(ss, o, 64);
    __shared__ float red[4];
    __shared__ float s_sc;
    int wave = tid >> 6, lane = tid & 63;
    if (lane == 0) red[wave] = ss;
    __syncthreads();
    if (tid == 0) s_sc = rsqrtf((red[0]+red[1]+red[2]+red[3]) / (float)cols + EPS_);
    __syncthreads();
    float sc = s_sc;
    for (int c = tid; c < cols; c += 256)
        op[c] = __float2bfloat16(ip[c] * sc * w[c]);
}

// ---------------------------------------------------------------------------
// RoPE helpers
// ---------------------------------------------------------------------------
#define ROPE_LC 0.28782313662425575f

__global__ __launch_bounds__(192) void build_q(const bf16* __restrict__ q,
                                               bf16* __restrict__ qf)
{
    int s = blockIdx.x, h = blockIdx.y, t = threadIdx.x;
    const float scale = 0.07216878364870323f;  // 1/sqrt(192)
    const bf16* src = q + (size_t)s * (H_*QKD_) + h * QKD_;
    bf16* dst = qf + ((size_t)h * S_ + s) * QKD_;
    if (t < NOPE_) {
        dst[t] = __float2bfloat16(__bfloat162float(src[t]) * scale);
    } else {
        int i = (t - NOPE_) & 31;
        bool hi = (t - NOPE_) >= 32;
        float a = __bfloat162float(src[NOPE_ + 2*i]);
        float b = __bfloat162float(src[NOPE_ + 2*i + 1]);
        float inv = __expf(-(float)i * ROPE_LC);
        float f = (float)s * inv, c, sn;
        sincosf(f, &sn, &c);
        float v = hi ? (b * c + a * sn) : (a * c - b * sn);
        dst[t] = __float2bfloat16(v * scale);
    }
}

__global__ __launch_bounds__(192) void build_k(const bf16* __restrict__ kv,
                                               const float* __restrict__ qakva32,
                                               bf16* __restrict__ kf)
{
    int s = blockIdx.x, h = blockIdx.y, t = threadIdx.x;
    const bf16* src = kv + (size_t)s * (H_*256) + h * 256;
    bf16* dst = kf + ((size_t)h * S_ + s) * QKD_;
    if (t < NOPE_) {
        dst[t] = src[t];
    } else {
        int i = (t - NOPE_) & 31;
        bool hi = (t - NOPE_) >= 32;
        const float* pe = qakva32 + (size_t)s * QKVN + (QR_ + KVR_);
        float a = pe[2*i], b = pe[2*i + 1];
        float inv = __expf(-(float)i * ROPE_LC);
        float f = (float)s * inv, c, sn;
        sincosf(f, &sn, &c);
        dst[t] = __float2bfloat16(hi ? (b * c + a * sn) : (a * c - b * sn));
    }
}

// ---------------------------------------------------------------------------
// Causal softmax, register-cached single global pass; zero-pads to 128 boundary.
// ---------------------------------------------------------------------------
__global__ __launch_bounds__(256) void softmax_k(bf16* __restrict__ Sc)
{
    int q = blockIdx.x, h = blockIdx.y;
    bf16* row = Sc + ((size_t)h * S_ + q) * S_;
    int n = q + 1;
    int klim = ((q >> 7) + 1) << 7;
    int tid = threadIdx.x, lane = tid & 63, wave = tid >> 6;
    __shared__ float red[4];
    __shared__ float bc;

    float v[8];
    #pragma unroll
    for (int k = 0; k < 8; ++k) {
        int c = tid + k * 256;
        v[k] = (c < n) ? __bfloat162float(row[c]) : -3.0e38f;
    }
    float mx = v[0];
    #pragma unroll
    for (int k = 1; k < 8; ++k) mx = fmaxf(mx, v[k]);
    for (int o = 32; o > 0; o >>= 1) mx = fmaxf(mx, __shfl_down(mx, o, 64));
    if (lane == 0) red[wave] = mx;
    __syncthreads();
    if (tid == 0) bc = fmaxf(fmaxf(red[0], red[1]), fmaxf(red[2], red[3]));
    __syncthreads();
    float m = bc;
    float sum = 0.f;
    #pragma unroll
    for (int k = 0; k < 8; ++k) {
        int c = tid + k * 256;
        v[k] = (c < n) ? __expf(v[k] - m) : 0.f;
        sum += v[k];
    }
    for (int o = 32; o > 0; o >>= 1) sum += __shfl_down(sum, o, 64);
    __syncthreads();
    if (lane == 0) red[wave] = sum;
    __syncthreads();
    if (tid == 0) bc = 1.0f / (red[0] + red[1] + red[2] + red[3]);
    __syncthreads();
    float inv = bc;
    #pragma unroll
    for (int k = 0; k < 8; ++k) {
        int c = tid + k * 256;
        if (c < klim) row[c] = __float2bfloat16(c < n ? v[k] * inv : 0.f);
    }
}

// ---------------------------------------------------------------------------
static inline void gemm(hipStream_t st, const bf16* A, const bf16* BT, void* C,
                        const float* bias, const float* res,
                        int M, int N, int K, int lda, int ldb, int ldc,
                        long long sA, long long sB, long long sC,
                        int batch, int mode, int causal, int ksplit = 1, int kchunk = 0)
{
    if (kchunk == 0) kchunk = K;
    dim3 g((N + 127) / 128, M / 128, batch * ksplit);
    gemm_k<<<g, 256, 0, st>>>(A, BT, C, bias, res, M, N, K, lda, ldb, ldc,
                              sA, sB, sC, mode, causal, ksplit, kchunk);
}

static inline void gemm256(hipStream_t st, const bf16* A, const bf16* BT, void* C,
                           const float* bias, int M, int N, int K,
                           int lda, int ldb, int ldc, long long sC,
                           int mode, int ksplit = 1, int kchunk = 0)
{
    if (kchunk == 0) kchunk = K;
    dim3 g((N + 255) / 256, M / 256, ksplit);
    gemm256_k<<<g, 512, 0, st>>>(A, BT, C, bias, M, N, K, lda, ldb, ldc,
                                 sC, mode, kchunk);
}

static inline void transw(hipStream_t st, const float* in, bf16* out, int R, int C)
{
    dim3 g((C + 31) / 32, (R + 31) / 32);
    transpose_w<<<g, dim3(32, 8), 0, st>>>(in, out, R, C);
}

extern "C" void kernel_launch(void* const* d_in, const int* in_sizes, int n_in,
                              void* d_out, int out_size, void* d_ws, size_t ws_size,
                              hipStream_t stream)
{
    const float* x        = (const float*)d_in[0];
    const float* norm1_w  = (const float*)d_in[1];
    const float* q_a_w    = (const float*)d_in[2];
    const float* q_a_ln_w = (const float*)d_in[3];
    const float* q_b_w    = (const float*)d_in[4];
    const float* kv_a_w   = (const float*)d_in[5];
    const float* kv_a_ln_w= (const float*)d_in[6];
    const float* kv_b_w   = (const float*)d_in[7];
    const float* o_w      = (const float*)d_in[8];
    const float* norm2_w  = (const float*)d_in[9];
    const float* ffn_w1   = (const float*)d_in[10];
    const float* ffn_b1   = (const float*)d_in[11];
    const float* ffn_w2   = (const float*)d_in[12];
    const float* ffn_b2   = (const float*)d_in[13];
    float* out = (float*)d_out;

    // ---- workspace layout ----
    size_t off = 0;
    auto alloc = [&](size_t bytes) -> void* {
        void* p = (char*)d_ws + off;
        off += (bytes + 255) & ~(size_t)255;
        return p;
    };
    bf16*  hs     = (bf16*) alloc((size_t)S_*D_*2);                 //  8.4 MB
    bf16*  wqakvT = (bf16*) alloc((size_t)QKVN*D_*2);               //  8.7 MB
    bf16*  wqbT   = (bf16*) alloc((size_t)(H_*QKD_)*QR_*2);         //  9.4 MB
    bf16*  wkvbT  = (bf16*) alloc((size_t)(H_*(NOPE_+VD_))*KVR_*2); //  4.2 MB
    bf16*  woT    = (bf16*) alloc((size_t)D_*(H_*VD_)*2);           //  8.4 MB
    bf16*  wf1T   = (bf16*) alloc((size_t)(4*D_)*D_*2);             // 33.6 MB
    bf16*  wf2T   = (bf16*) alloc((size_t)D_*(4*D_)*2);             // 33.6 MB
    float* qakva32= (float*)alloc((size_t)S_*QKVN*4);               // 17.3 MB
    bf16*  qln    = (bf16*) alloc((size_t)S_*QR_*2);                //  6.3 MB
    bf16*  kvln   = (bf16*) alloc((size_t)S_*KVR_*2);               //  2.1 MB
    bf16*  qb     = (bf16*) alloc((size_t)S_*H_*QKD_*2);            // 12.6 MB
    bf16*  kvb    = (bf16*) alloc((size_t)S_*H_*(NOPE_+VD_)*2);     // 16.8 MB
    bf16*  qf     = (bf16*) alloc((size_t)H_*S_*QKD_*2);            // 12.6 MB
    bf16*  kf     = (bf16*) alloc((size_t)H_*S_*QKD_*2);            // 12.6 MB
    bf16*  vT     = (bf16*) alloc((size_t)H_*VD_*S_*2);             //  8.4 MB
    bf16*  Sc     = (bf16*) alloc((size_t)8*S_*S_*2);               // 67.1 MB
    // overlays (lifetimes disjoint):
    float* qakvaP = (float*)Sc;       // 3 x 17.3 MB in Sc            (pre-scores)
    float* qbP    = (float*)Sc;       // 2 x 25.2 MB in Sc            (pre-scores)
    float* pvP    = (float*)qakva32;  // 32 x 1.05 MB over qakva32+qln+kvln+qb
    float* oP     = (float*)Sc;       // 4 x 16.8 MB = 67.1 MB (Sc dead post-attn)
    float* f2P    = (float*)d_ws;     // 4 x 16.8 MB over hs..wf1T (dead at FFN2)
    float* x2     = qakva32;          // f32 residual, written post-attention
    bf16*  h2     = qb;               // post-attention rmsnorm output
    bf16*  ao     = kvb;              // attn out bf16 [S][2048]
    bf16*  a1     = Sc;               // ffn1 activation 33.6 MB (Sc dead post-attn)

    // ---- weight transposes (qa+kva fused along N) ----
    transw(stream, q_a_w,  wqakvT,                    D_,  QR_);
    transw(stream, kv_a_w, wqakvT + (size_t)QR_ * D_, D_,  KVR_+ROPE_);
    transw(stream, q_b_w,  wqbT,  QR_, H_*QKD_);
    transw(stream, kv_b_w, wkvbT, KVR_, H_*(NOPE_+VD_));
    transw(stream, o_w,    woT,   H_*VD_, D_);
    transw(stream, ffn_w1, wf1T,  D_,  4*D_);
    transw(stream, ffn_w2, wf2T,  4*D_, D_);

    // ---- pre-attention pipeline ----
    rmsnorm_k<<<S_, 256, 0, stream>>>(x, norm1_w, hs, D_, D_, D_);

    // fused qa+kva: 256^2 8-phase, split-K 3 (216 blocks) -> f32 qakva32
    gemm256(stream, hs, wqakvT, qakvaP, nullptr, S_, QKVN, D_, D_, D_, QKVN,
            (long long)S_*QKVN, 6, 3, 768);
    red_k<<<1024, 256, 0, stream>>>(qakvaP, (long long)S_*QKVN/4, 3, nullptr, nullptr, 1,
                                    qakva32, nullptr, (long long)S_*QKVN/4);

    rmsnorm_k<<<S_, 256, 0, stream>>>(qakva32, q_a_ln_w, qln, QR_, QKVN, QR_);
    gemm256(stream, qln, wqbT, qbP, nullptr, S_, H_*QKD_, QR_, QR_, QR_, H_*QKD_,
            (long long)S_*(H_*QKD_), 6, 2, 768);
    red_k<<<1024, 256, 0, stream>>>(qbP, (long long)S_*(H_*QKD_)/4, 2, nullptr, nullptr, 1,
                                    nullptr, qb, (long long)S_*(H_*QKD_)/4);

    rmsnorm_k<<<S_, 256, 0, stream>>>(qakva32 + QR_, kv_a_ln_w, kvln, KVR_, QKVN, KVR_);
    gemm(stream, kvln, wkvbT, kvb, nullptr, nullptr, S_, H_*(NOPE_+VD_), KVR_,
         KVR_, KVR_, H_*(NOPE_+VD_), 0, 0, 0, 1, 1, 0);

    build_q<<<dim3(S_, H_), 192, 0, stream>>>(qb, qf);
    build_k<<<dim3(S_, H_), 192, 0, stream>>>(kvb, qakva32, kf);
    transpose_v<<<dim3(VD_/32, S_/32, H_), dim3(32, 8), 0, stream>>>(kvb, vT);

    // ---- attention: 2 groups of 8 heads; PV split-K 4 with partials ----
    for (int g = 0; g < 2; ++g) {
        const bf16* qfg = qf + (size_t)g * 8 * S_ * QKD_;
        const bf16* kfg = kf + (size_t)g * 8 * S_ * QKD_;
        const bf16* vTg = vT + (size_t)g * 8 * VD_ * S_;
        gemm(stream, qfg, kfg, Sc, nullptr, nullptr,
             S_, S_, QKD_, QKD_, QKD_, S_,
             (long long)S_*QKD_, (long long)S_*QKD_, (long long)S_*S_, 8, 1, 1);
        softmax_k<<<dim3(S_, 8), 256, 0, stream>>>(Sc);
        gemm(stream, Sc, vTg, pvP, nullptr, nullptr,
             S_, VD_, S_, S_, S_, VD_,
             (long long)S_*S_, (long long)VD_*S_, (long long)S_*VD_, 8, 6, 2, 4, 512);
        pv_red<<<dim3(S_, 8), 128, 0, stream>>>(pvP, ao, g);
    }

    // ---- o-projection + residual: 256^2, split-K 4 (256 blocks), partials in Sc ----
    gemm256(stream, ao, woT, oP, nullptr, S_, D_, H_*VD_, H_*VD_, H_*VD_, D_,
            (long long)S_*D_, 6, 4, 512);
    red_k<<<1024, 256, 0, stream>>>(oP, (long long)S_*D_/4, 4, x, nullptr, 1,
                                    x2, nullptr, (long long)S_*D_/4);

    // ---- FFN ----
    rmsnorm_k<<<S_, 256, 0, stream>>>(x2, norm2_w, h2, D_, D_, D_);
    gemm256(stream, h2, wf1T, a1, ffn_b1, S_, 4*D_, D_, D_, D_, 4*D_,
            0, 3, 1, 0);
    gemm256(stream, a1, wf2T, f2P, nullptr, S_, D_, 4*D_, 4*D_, 4*D_, D_,
            (long long)S_*D_, 6, 4, 2048);
    red_k<<<1024, 256, 0, stream>>>(f2P, (long long)S_*D_/4, 4, x2, ffn_b2, D_/4,
                                    out, nullptr, (long long)S_*D_/4);
}

// Round 11
// 904.960 us; speedup vs baseline: 1.2723x; 1.2723x over previous
//
#include <hip/hip_runtime.h>
#include <hip/hip_bf16.h>

typedef __hip_bfloat16 bf16;
using bf16x8 = __attribute__((ext_vector_type(8))) __bf16;
using f32x4  = __attribute__((ext_vector_type(4))) float;

#define S_   2048
#define D_   2048
#define H_   16
#define QR_  1536
#define KVR_ 512
#define NOPE_ 128
#define ROPE_ 64
#define VD_  128
#define QKD_ 192
#define EPS_ 1e-5f
#define QKVN 2112   // QR_ + KVR_ + ROPE_ (fused qa+kva output width)

// async global->LDS, 16B per lane; LDS dest = wave-uniform base + lane*16
#define GLDS16(g, l) \
    __builtin_amdgcn_global_load_lds((const __attribute__((address_space(1))) void*)(g), \
                                     (__attribute__((address_space(3))) void*)(l), 16, 0, 0)

#define PIPE_WAIT4 asm volatile("s_waitcnt vmcnt(4)\n\ts_barrier" ::: "memory")
#define PIPE_WAIT0 asm volatile("s_waitcnt vmcnt(0)\n\ts_barrier" ::: "memory")

// ---------------------------------------------------------------------------
// bf16 MFMA GEMM (128x128 tile, 4 waves) — retained for causal scores / PV /
// small-K kv_b. 3-stage pipelined, vmcnt(4) barriers.
// mode: 0=f32, 1=bf16, 2=f32+res, 3=bf16 gelu(x+bias), 4=f32+bias+res, 6=f32 partial
// causal: 0 none, 1 skip upper tiles, 2 K limited to diagonal
// ---------------------------------------------------------------------------
__global__ __launch_bounds__(256) void gemm_k(
    const bf16* __restrict__ A, const bf16* __restrict__ BT, void* __restrict__ Cv,
    const float* __restrict__ bias, const float* __restrict__ res,
    int M, int N, int K, int lda, int ldb, int ldc,
    long long strideA, long long strideB, long long strideC,
    int mode, int causal, int ksplit, int kchunk)
{
    int bn = blockIdx.x, bm = blockIdx.y;
    int bzC = blockIdx.z;
    int bz = bzC, kc = 0;
    if (ksplit > 1) { kc = bzC % ksplit; bz = bzC / ksplit; }
    if (causal == 1 && bn > bm) return;
    A  += (size_t)bz * strideA;
    BT += (size_t)bz * strideB;

    int k_end = K;
    if (causal == 2) { int kl = (bm + 1) * 128; if (kl < k_end) k_end = kl; }
    int k_begin = kc * kchunk;
    if (k_begin + kchunk < k_end) k_end = k_begin + kchunk;
    if (k_begin >= k_end) return;
    int nIter = (k_end - k_begin) >> 5;

    __shared__ bf16 sA[3 * 128 * 32];
    __shared__ bf16 sB[3 * 128 * 32];

    int tid  = threadIdx.x;
    int lane = tid & 63, wave = tid >> 6;
    int wr = wave >> 1, wc = wave & 1;
    int fr = lane & 15, fq = lane >> 4;

    int row0 = bm * 128, col0 = bn * 128;

    int srow = wave * 16 + (lane >> 2);
    int sko  = (lane & 3) * 8;
    const bf16* ga0 = A + (size_t)(row0 + srow) * lda + sko;
    const bf16* ga1 = ga0 + (size_t)64 * lda;
    int bn0 = col0 + srow;      if (bn0 > N - 1) bn0 = N - 1;
    int bn1 = col0 + srow + 64; if (bn1 > N - 1) bn1 = N - 1;
    const bf16* gb0 = BT + (size_t)bn0 * ldb + sko;
    const bf16* gb1 = BT + (size_t)bn1 * ldb + sko;
    bf16* lA0 = &sA[(wave * 16) * 32];
    bf16* lA1 = &sA[(64 + wave * 16) * 32];
    bf16* lB0 = &sB[(wave * 16) * 32];
    bf16* lB1 = &sB[(64 + wave * 16) * 32];

#define STAGE(ofs, k0) do {                  \
        GLDS16(ga0 + (k0), lA0 + (ofs));     \
        GLDS16(ga1 + (k0), lA1 + (ofs));     \
        GLDS16(gb0 + (k0), lB0 + (ofs));     \
        GLDS16(gb1 + (k0), lB1 + (ofs));     \
    } while (0)

    f32x4 acc[4][4] = {};

#define COMPUTE(ofs) do {                                                           \
        bf16x8 af[4], bv[4];                                                        \
        _Pragma("unroll")                                                           \
        for (int i = 0; i < 4; ++i)                                                 \
            af[i] = *(const bf16x8*)&sA[(ofs) + (wr*64 + i*16 + fr)*32 + fq*8];     \
        _Pragma("unroll")                                                           \
        for (int j = 0; j < 4; ++j)                                                 \
            bv[j] = *(const bf16x8*)&sB[(ofs) + (wc*64 + j*16 + fr)*32 + fq*8];     \
        _Pragma("unroll")                                                           \
        for (int i = 0; i < 4; ++i)                                                 \
            _Pragma("unroll")                                                       \
            for (int j = 0; j < 4; ++j)                                             \
                acc[i][j] = __builtin_amdgcn_mfma_f32_16x16x32_bf16(af[i], bv[j], acc[i][j], 0, 0, 0); \
    } while (0)

    STAGE(0, k_begin);
    if (nIter > 1) STAGE(4096, k_begin + 32);

    int curo = 0, pfo = 8192;
    int it = 0;
    for (; it < nIter - 1; ++it) {
        PIPE_WAIT4;
        if (it + 2 < nIter) STAGE(pfo, k_begin + (it + 2) * 32);
        COMPUTE(curo);
        curo += 4096; if (curo == 12288) curo = 0;
        pfo  += 4096; if (pfo  == 12288) pfo  = 0;
    }
    PIPE_WAIT0;
    COMPUTE(curo);
#undef STAGE
#undef COMPUTE

    #pragma unroll
    for (int i = 0; i < 4; ++i) {
        #pragma unroll
        for (int j = 0; j < 4; ++j) {
            int gc = col0 + wc*64 + j*16 + fr;
            if (gc >= N) continue;
            #pragma unroll
            for (int r = 0; r < 4; ++r) {
                int gr = row0 + wr*64 + i*16 + fq*4 + r;
                float v = acc[i][j][r];
                size_t off = (size_t)bzC * strideC + (size_t)gr * ldc + gc;
                if (mode == 0 || mode == 6) {
                    ((float*)Cv)[off] = v;
                } else if (mode == 1) {
                    ((bf16*)Cv)[off] = __float2bfloat16(v);
                } else if (mode == 2) {
                    ((float*)Cv)[off] = v + res[(size_t)gr * ldc + gc];
                } else if (mode == 3) {
                    float t = v + bias[gc];
                    t = 0.5f * t * (1.0f + erff(t * 0.70710678118654752f));
                    ((bf16*)Cv)[off] = __float2bfloat16(t);
                } else {
                    ((float*)Cv)[off] = v + bias[gc] + res[(size_t)gr * ldc + gc];
                }
            }
        }
    }
}

// ---------------------------------------------------------------------------
// 256x256-tile, 8-wave, 8-phase bf16 GEMM (R2-verified variant).
//  - BK=64, double-buffered LDS (128 KiB), one K-tile per buffer.
//  - chunk-XOR swizzle: LDS dest linear (global_load_lds), SOURCE pre-swizzled,
//    ds_read applies the same involution -> conflict-free (verified 0).
//  - per tile: ph1 reads A-lo+all B + stages A1(t+1); ph2 reads A-hi,
//    stages B0(t+2); ph3 stages B1(t+2); ph4 stages A0(t+2) + vmcnt(6).
//  - NOTE (R2-R5 lesson): this structure is near its LDS-read-throughput
//    ceiling (~192 ds_read_b128/tile/CU ≈ 2300 cyc vs 620 cyc MFMA ->
//    ~27% MfmaUtil ceiling). Schedule variants (R3 quadrant order, R4
//    pipelined lgkm gates, R5 single-barrier) are null or race.
// mode: 0=f32, 1=bf16, 3=bf16 gelu(x+bias), 6=f32 partial (plane = blockIdx.z)
// ---------------------------------------------------------------------------
__global__ __launch_bounds__(512, 2) void gemm256_k(
    const bf16* __restrict__ A, const bf16* __restrict__ BT, void* __restrict__ Cv,
    const float* __restrict__ bias,
    int M, int N, int K, int lda, int ldb, int ldc,
    long long strideC, int mode, int kchunk)
{
    int bn = blockIdx.x, bm = blockIdx.y, kc = blockIdx.z;
    int k_begin = kc * kchunk;
    int k_end = (k_begin + kchunk < K) ? (k_begin + kchunk) : K;
    int NT = (k_end - k_begin) >> 6;

    __shared__ __align__(16) bf16 sA[2 * 256 * 64];   // 64 KiB
    __shared__ __align__(16) bf16 sB[2 * 256 * 64];   // 64 KiB

    int tid = threadIdx.x;
    int lane = tid & 63, w = tid >> 6;
    int wr = w >> 2, wc = w & 3;            // 2x4 wave grid; wave owns 128x64
    int fr = lane & 15, fq = lane >> 4;
    int row0 = bm * 256, col0 = bn * 256;

    int g0 = tid, g1 = tid + 512;
    int r0 = g0 >> 3, l0 = (g0 & 7) ^ (r0 & 7);
    int r1 = g1 >> 3, l1 = (g1 & 7) ^ (r1 & 7);
    const bf16* gA00 = A + (size_t)(row0 + r0) * lda + k_begin + l0 * 8;
    const bf16* gA01 = A + (size_t)(row0 + r1) * lda + k_begin + l1 * 8;
    const bf16* gA10 = gA00 + (size_t)128 * lda;
    const bf16* gA11 = gA01 + (size_t)128 * lda;
    int c00 = col0 + r0;       if (c00 > N - 1) c00 = N - 1;
    int c01 = col0 + r1;       if (c01 > N - 1) c01 = N - 1;
    int c10 = col0 + 128 + r0; if (c10 > N - 1) c10 = N - 1;
    int c11 = col0 + 128 + r1; if (c11 > N - 1) c11 = N - 1;
    const bf16* gB00 = BT + (size_t)c00 * ldb + k_begin + l0 * 8;
    const bf16* gB01 = BT + (size_t)c01 * ldb + k_begin + l1 * 8;
    const bf16* gB10 = BT + (size_t)c10 * ldb + k_begin + l0 * 8;
    const bf16* gB11 = BT + (size_t)c11 * ldb + k_begin + l1 * 8;

#define ST_HALF(arr, bofs, p0, p1, t) do {                                  \
        GLDS16((p0) + (size_t)(t) * 64, (arr) + (bofs) + w * 512);          \
        GLDS16((p1) + (size_t)(t) * 64, (arr) + (bofs) + w * 512 + 4096);   \
    } while (0)
#define ST_A0(b, t) ST_HALF(sA, (b) * 16384,        gA00, gA01, t)
#define ST_A1(b, t) ST_HALF(sA, (b) * 16384 + 8192, gA10, gA11, t)
#define ST_B0(b, t) ST_HALF(sB, (b) * 16384,        gB00, gB01, t)
#define ST_B1(b, t) ST_HALF(sB, (b) * 16384 + 8192, gB10, gB11, t)

    int arow = (wr * 128 + fr) * 64;
    int brow = (wc * 64 + fr) * 64;
    int pk0 = (fq ^ (fr & 7)) * 8;
    int pk1 = pk0 ^ 32;

    f32x4 acc[8][4] = {};

#define MFMA_QUAD(AF, IOFF, N0) do {                                        \
        __builtin_amdgcn_s_setprio(1);                                      \
        _Pragma("unroll")                                                   \
        for (int m = 0; m < 4; ++m) {                                       \
            _Pragma("unroll")                                               \
            for (int n = 0; n < 2; ++n) {                                   \
                acc[(IOFF)+m][(N0)+n] = __builtin_amdgcn_mfma_f32_16x16x32_bf16( \
                    AF[m][0], bfr[(N0)+n][0], acc[(IOFF)+m][(N0)+n], 0, 0, 0);   \
                acc[(IOFF)+m][(N0)+n] = __builtin_amdgcn_mfma_f32_16x16x32_bf16( \
                    AF[m][1], bfr[(N0)+n][1], acc[(IOFF)+m][(N0)+n], 0, 0, 0);   \
            }                                                               \
        }                                                                   \
        __builtin_amdgcn_s_setprio(0);                                      \
    } while (0)

    ST_A0(0, 0); ST_A1(0, 0); ST_B0(0, 0); ST_B1(0, 0);
    if (NT > 1) { ST_B0(1, 1); ST_B1(1, 1); ST_A0(1, 1); }
    if (NT > 1) asm volatile("s_waitcnt vmcnt(6)" ::: "memory");
    else        asm volatile("s_waitcnt vmcnt(0)" ::: "memory");
    __builtin_amdgcn_s_barrier();

    for (int t = 0; t < NT; ++t) {
        int buf = t & 1;
        int sbase = buf * 16384;
        bf16x8 aflo[4][2], afhi[4][2], bfr[4][2];

        // ---- phase 1: read A m0-3 (8) + B n0-3 (8); stage A1(t+1) ----
        #pragma unroll
        for (int m = 0; m < 4; ++m) {
            aflo[m][0] = *(const bf16x8*)&sA[sbase + arow + m*1024 + pk0];
            aflo[m][1] = *(const bf16x8*)&sA[sbase + arow + m*1024 + pk1];
        }
        #pragma unroll
        for (int n = 0; n < 4; ++n) {
            bfr[n][0] = *(const bf16x8*)&sB[sbase + brow + n*1024 + pk0];
            bfr[n][1] = *(const bf16x8*)&sB[sbase + brow + n*1024 + pk1];
        }
        if (t + 1 < NT) ST_A1((t + 1) & 1, t + 1);
        asm volatile("s_waitcnt lgkmcnt(8)" ::: "memory");
        __builtin_amdgcn_s_barrier();
        asm volatile("s_waitcnt lgkmcnt(0)" ::: "memory");
        __builtin_amdgcn_sched_barrier(0);
        MFMA_QUAD(aflo, 0, 0);
        __builtin_amdgcn_s_barrier();

        // ---- phase 2: read A m4-7 (8); stage B0(t+2) ----
        #pragma unroll
        for (int m = 0; m < 4; ++m) {
            afhi[m][0] = *(const bf16x8*)&sA[sbase + arow + 4096 + m*1024 + pk0];
            afhi[m][1] = *(const bf16x8*)&sA[sbase + arow + 4096 + m*1024 + pk1];
        }
        if (t + 2 < NT) ST_B0(buf, t + 2);
        __builtin_amdgcn_s_barrier();
        asm volatile("s_waitcnt lgkmcnt(0)" ::: "memory");
        __builtin_amdgcn_sched_barrier(0);
        MFMA_QUAD(aflo, 0, 2);
        __builtin_amdgcn_s_barrier();

        // ---- phase 3: stage B1(t+2); MFMA hi x lo ----
        if (t + 2 < NT) ST_B1(buf, t + 2);
        __builtin_amdgcn_s_barrier();
        asm volatile("s_waitcnt lgkmcnt(0)" ::: "memory");
        __builtin_amdgcn_sched_barrier(0);
        MFMA_QUAD(afhi, 4, 0);
        __builtin_amdgcn_s_barrier();

        // ---- phase 4: stage A0(t+2); counted vmcnt; MFMA hi x hi ----
        if (t + 2 < NT) ST_A0(buf, t + 2);
        if (t < NT - 2) asm volatile("s_waitcnt vmcnt(6)" ::: "memory");
        else            asm volatile("s_waitcnt vmcnt(0)" ::: "memory");
        __builtin_amdgcn_s_barrier();
        MFMA_QUAD(afhi, 4, 2);
        __builtin_amdgcn_s_barrier();
    }
#undef MFMA_QUAD
#undef ST_A0
#undef ST_A1
#undef ST_B0
#undef ST_B1
#undef ST_HALF

    #pragma unroll
    for (int i = 0; i < 8; ++i) {
        #pragma unroll
        for (int j = 0; j < 4; ++j) {
            int gc = col0 + wc*64 + j*16 + fr;
            if (gc >= N) continue;
            #pragma unroll
            for (int r = 0; r < 4; ++r) {
                int gr = row0 + wr*128 + i*16 + fq*4 + r;
                float v = acc[i][j][r];
                size_t off = (size_t)kc * strideC + (size_t)gr * ldc + gc;
                if (mode == 0 || mode == 6) {
                    ((float*)Cv)[off] = v;
                } else if (mode == 1) {
                    ((bf16*)Cv)[off] = __float2bfloat16(v);
                } else {  // mode 3: gelu(x + bias) -> bf16
                    float tt = v + bias[gc];
                    tt = 0.5f * tt * (1.0f + erff(tt * 0.70710678118654752f));
                    ((bf16*)Cv)[off] = __float2bfloat16(tt);
                }
            }
        }
    }
}

// ---------------------------------------------------------------------------
// Split-K reduce: dst = sum of nch partial planes (+res)(+bias), float4.
// ---------------------------------------------------------------------------
__global__ __launch_bounds__(256) void red_k(const float* __restrict__ part,
        long long pstride4, int nch, const float* __restrict__ res,
        const float* __restrict__ bias, long long cols4,
        float* __restrict__ dstF, bf16* __restrict__ dstB, long long n4)
{
    long long i = (long long)blockIdx.x * 256 + threadIdx.x;
    long long stride = (long long)gridDim.x * 256;
    for (; i < n4; i += stride) {
        float4 v = ((const float4*)part)[i];
        for (int k = 1; k < nch; ++k) {
            float4 p = ((const float4*)part)[i + k * pstride4];
            v.x += p.x; v.y += p.y; v.z += p.z; v.w += p.w;
        }
        if (res) {
            float4 rr = ((const float4*)res)[i];
            v.x += rr.x; v.y += rr.y; v.z += rr.z; v.w += rr.w;
        }
        if (bias) {
            float4 b = ((const float4*)bias)[i % cols4];
            v.x += b.x; v.y += b.y; v.z += b.z; v.w += b.w;
        }
        if (dstB) {
            ushort4 o;
            bf16 t0 = __float2bfloat16(v.x); o.x = *(unsigned short*)&t0;
            bf16 t1 = __float2bfloat16(v.y); o.y = *(unsigned short*)&t1;
            bf16 t2 = __float2bfloat16(v.z); o.z = *(unsigned short*)&t2;
            bf16 t3 = __float2bfloat16(v.w); o.w = *(unsigned short*)&t3;
            ((ushort4*)dstB)[i] = o;
        } else {
            ((float4*)dstF)[i] = v;
        }
    }
}

// ---------------------------------------------------------------------------
// Fused: qakva split-K(3) reduce + rmsnorm(q_a_ln) + rmsnorm(kv_a_ln) + pe.
// One block per row s. part = [3][S][QKVN] f32.
// ---------------------------------------------------------------------------
__global__ __launch_bounds__(256) void red_qakva_k(const float* __restrict__ part,
        const float* __restrict__ qw, const float* __restrict__ kvw,
        bf16* __restrict__ qln, bf16* __restrict__ kvln, float* __restrict__ pe)
{
    int row = blockIdx.x, tid = threadIdx.x;
    const float* p0 = part + (size_t)row * QKVN;
    const float* p1 = p0 + (size_t)S_ * QKVN;
    const float* p2 = p1 + (size_t)S_ * QKVN;
    float v[9];
    float ssq_q = 0.f, ssq_kv = 0.f;
    #pragma unroll
    for (int k = 0; k < 9; ++k) {
        int c = tid + k * 256;
        float s = 0.f;
        if (c < QKVN) s = p0[c] + p1[c] + p2[c];
        v[k] = s;
        if (c < QR_) ssq_q = fmaf(s, s, ssq_q);
        else if (c < QR_ + KVR_) ssq_kv = fmaf(s, s, ssq_kv);
    }
    for (int o = 32; o > 0; o >>= 1) {
        ssq_q  += __shfl_down(ssq_q,  o, 64);
        ssq_kv += __shfl_down(ssq_kv, o, 64);
    }
    __shared__ float rq[4], rkv[4];
    __shared__ float sq, skv;
    int wave = tid >> 6, lane = tid & 63;
    if (lane == 0) { rq[wave] = ssq_q; rkv[wave] = ssq_kv; }
    __syncthreads();
    if (tid == 0) {
        sq  = rsqrtf((rq[0]+rq[1]+rq[2]+rq[3])   / (float)QR_  + EPS_);
        skv = rsqrtf((rkv[0]+rkv[1]+rkv[2]+rkv[3]) / (float)KVR_ + EPS_);
    }
    __syncthreads();
    float a = sq, b = skv;
    #pragma unroll
    for (int k = 0; k < 9; ++k) {
        int c = tid + k * 256;
        if (c < QR_) {
            qln[(size_t)row * QR_ + c] = __float2bfloat16(v[k] * a * qw[c]);
        } else if (c < QR_ + KVR_) {
            kvln[(size_t)row * KVR_ + (c - QR_)] = __float2bfloat16(v[k] * b * kvw[c - QR_]);
        } else if (c < QKVN) {
            pe[(size_t)row * ROPE_ + (c - QR_ - KVR_)] = v[k];
        }
    }
}

#define ROPE_LC 0.28782313662425575f

// ---------------------------------------------------------------------------
// Fused: qb split-K(2) reduce + build_q (scale nope, rope pe) -> qf[h][s][d].
// One block per row s. part = [2][S][H*QKD] f32.
// ---------------------------------------------------------------------------
__global__ __launch_bounds__(256) void red_buildq_k(const float* __restrict__ part,
                                                    bf16* __restrict__ qf)
{
    int s = blockIdx.x, tid = threadIdx.x;
    const float* p0 = part + (size_t)s * (H_*QKD_);
    const float* p1 = p0 + (size_t)S_ * (H_*QKD_);
    __shared__ float rowv[H_*QKD_];   // 3072 f32 = 12 KB
    for (int c = tid; c < H_*QKD_; c += 256) rowv[c] = p0[c] + p1[c];
    __syncthreads();
    const float scale = 0.07216878364870323f;  // 1/sqrt(192)
    for (int o = tid; o < H_*QKD_; o += 256) {
        int h = o / QKD_, t = o - h*QKD_;
        const float* src = rowv + h*QKD_;
        float outv;
        if (t < NOPE_) {
            outv = src[t] * scale;
        } else {
            int i = (t - NOPE_) & 31;
            bool hi = (t - NOPE_) >= 32;
            float a = src[NOPE_ + 2*i], b = src[NOPE_ + 2*i + 1];
            float inv = __expf(-(float)i * ROPE_LC);
            float f = (float)s * inv, c2, sn;
            sincosf(f, &sn, &c2);
            outv = (hi ? (b * c2 + a * sn) : (a * c2 - b * sn)) * scale;
        }
        qf[((size_t)h * S_ + s) * QKD_ + t] = __float2bfloat16(outv);
    }
}

// ---------------------------------------------------------------------------
// Fused: o-proj split-K(4) reduce + residual add + rmsnorm(norm2) -> x2, h2.
// One block per row. part = [4][S][D] f32.
// ---------------------------------------------------------------------------
__global__ __launch_bounds__(256) void red_o_rms_k(const float* __restrict__ part,
        const float* __restrict__ x, const float* __restrict__ w,
        float* __restrict__ x2, bf16* __restrict__ h2)
{
    int row = blockIdx.x, tid = threadIdx.x;
    const float* p = part + (size_t)row * D_;
    const long long pl = (long long)S_ * D_;
    float v[8];
    float ssq = 0.f;
    #pragma unroll
    for (int k = 0; k < 8; ++k) {
        int c = tid + k * 256;
        float s = p[c] + p[c + pl] + p[c + 2*pl] + p[c + 3*pl] + x[(size_t)row * D_ + c];
        v[k] = s;
        ssq = fmaf(s, s, ssq);
        x2[(size_t)row * D_ + c] = s;
    }
    for (int o = 32; o > 0; o >>= 1) ssq += __shfl_down(ssq, o, 64);
    __shared__ float red[4];
    __shared__ float s_sc;
    int wave = tid >> 6, lane = tid & 63;
    if (lane == 0) red[wave] = ssq;
    __syncthreads();
    if (tid == 0) s_sc = rsqrtf((red[0]+red[1]+red[2]+red[3]) / (float)D_ + EPS_);
    __syncthreads();
    float sc = s_sc;
    #pragma unroll
    for (int k = 0; k < 8; ++k) {
        int c = tid + k * 256;
        h2[(size_t)row * D_ + c] = __float2bfloat16(v[k] * sc * w[c]);
    }
}

// PV split-K reduce with causal chunk-validity: part[head][4][S][128] (kchunk=512)
__global__ __launch_bounds__(128) void pv_red(const float* __restrict__ part,
                                              bf16* __restrict__ ao, int grp)
{
    int r = blockIdx.x, head = blockIdx.y, d = threadIdx.x;
    int nv = ((r >> 7) + 4) >> 2;
    const float* p = part + ((size_t)head * 4) * S_ * VD_ + (size_t)r * VD_ + d;
    float s = 0.f;
    for (int k = 0; k < nv; ++k) s += p[(size_t)k * S_ * VD_];
    ao[(size_t)r * (H_ * VD_) + grp * 1024 + head * VD_ + d] = __float2bfloat16(s);
}

// ---------------------------------------------------------------------------
// Vectorized weight transpose + f32->bf16: in[R,C] f32 -> out[C,R] bf16.
// 32-row x 128-col tiles; float4 reads; R must be a multiple of 32.
// ---------------------------------------------------------------------------
__global__ __launch_bounds__(256) void transpose_w4(const float* __restrict__ in,
                                                    bf16* __restrict__ out, int R, int C)
{
    __shared__ float t[128][33];
    int c0 = blockIdx.x * 128, r0 = blockIdx.y * 32;
    int tx = threadIdx.x, ty = threadIdx.y;   // (32, 8)
    #pragma unroll
    for (int j = 0; j < 4; ++j) {
        int r = r0 + ty + j*8;
        int c = c0 + tx*4;
        if (c + 3 < C) {
            float4 v4 = *(const float4*)&in[(size_t)r * C + c];
            t[tx*4+0][ty+j*8] = v4.x; t[tx*4+1][ty+j*8] = v4.y;
            t[tx*4+2][ty+j*8] = v4.z; t[tx*4+3][ty+j*8] = v4.w;
        } else {
            #pragma unroll
            for (int kk = 0; kk < 4; ++kk) {
                int cc = c + kk;
                t[tx*4+kk][ty+j*8] = (cc < C) ? in[(size_t)r * C + cc] : 0.f;
            }
        }
    }
    __syncthreads();
    #pragma unroll
    for (int j = 0; j < 16; ++j) {
        int cl = ty + j*8;
        int c = c0 + cl;
        if (c < C) out[(size_t)c * R + r0 + tx] = __float2bfloat16(t[cl][tx]);
    }
}

// vT[h][d][s] = kv[s][h*256 + 128 + d]
__global__ __launch_bounds__(256) void transpose_v(const bf16* __restrict__ kv,
                                                   bf16* __restrict__ vT)
{
    __shared__ bf16 t[32][33];
    int h = blockIdx.z;
    int d0 = blockIdx.x * 32, s0 = blockIdx.y * 32;
    int tx = threadIdx.x, ty = threadIdx.y;
    for (int j = ty; j < 32; j += 8)
        t[j][tx] = kv[(size_t)(s0 + j) * (H_*256) + h*256 + 128 + d0 + tx];
    __syncthreads();
    for (int j = ty; j < 32; j += 8)
        vT[((size_t)h * VD_ + d0 + j) * S_ + s0 + tx] = t[tx][j];
}

// ---------------------------------------------------------------------------
// RMSNorm: f32 in (strided) -> bf16 out
// ---------------------------------------------------------------------------
__global__ __launch_bounds__(256) void rmsnorm_k(const float* __restrict__ in,
                                                 const float* __restrict__ w,
                                                 bf16* __restrict__ out,
                                                 int cols, int istride, int ostride)
{
    int row = blockIdx.x, tid = threadIdx.x;
    const float* ip = in + (size_t)row * istride;
    bf16* op = out + (size_t)row * ostride;
    float ss = 0.f;
    for (int c = tid; c < cols; c += 256) { float v = ip[c]; ss = fmaf(v, v, ss); }
    for (int o = 32; o > 0; o >>= 1) ss += __shfl_down(ss, o, 64);
    __shared__ float red[4];
    __shared__ float s_sc;
    int wave = tid >> 6, lane = tid & 63;
    if (lane == 0) red[wave] = ss;
    __syncthreads();
    if (tid == 0) s_sc = rsqrtf((red[0]+red[1]+red[2]+red[3]) / (float)cols + EPS_);
    __syncthreads();
    float sc = s_sc;
    for (int c = tid; c < cols; c += 256)
        op[c] = __float2bfloat16(ip[c] * sc * w[c]);
}

// kf: nope from kv[s][h*256+d]; roped pe from pe[s][0..63]
__global__ __launch_bounds__(192) void build_k(const bf16* __restrict__ kv,
                                               const float* __restrict__ pe,
                                               bf16* __restrict__ kf)
{
    int s = blockIdx.x, h = blockIdx.y, t = threadIdx.x;
    const bf16* src = kv + (size_t)s * (H_*256) + h * 256;
    bf16* dst = kf + ((size_t)h * S_ + s) * QKD_;
    if (t < NOPE_) {
        dst[t] = src[t];
    } else {
        int i = (t - NOPE_) & 31;
        bool hi = (t - NOPE_) >= 32;
        const float* p = pe + (size_t)s * ROPE_;
        float a = p[2*i], b = p[2*i + 1];
        float inv = __expf(-(float)i * ROPE_LC);
        float f = (float)s * inv, c, sn;
        sincosf(f, &sn, &c);
        dst[t] = __float2bfloat16(hi ? (b * c + a * sn) : (a * c - b * sn));
    }
}

// ---------------------------------------------------------------------------
// Causal softmax, register-cached single global pass; zero-pads to 128 boundary.
// ---------------------------------------------------------------------------
__global__ __launch_bounds__(256) void softmax_k(bf16* __restrict__ Sc)
{
    int q = blockIdx.x, h = blockIdx.y;
    bf16* row = Sc + ((size_t)h * S_ + q) * S_;
    int n = q + 1;
    int klim = ((q >> 7) + 1) << 7;
    int tid = threadIdx.x, lane = tid & 63, wave = tid >> 6;
    __shared__ float red[4];
    __shared__ float bc;

    float v[8];
    #pragma unroll
    for (int k = 0; k < 8; ++k) {
        int c = tid + k * 256;
        v[k] = (c < n) ? __bfloat162float(row[c]) : -3.0e38f;
    }
    float mx = v[0];
    #pragma unroll
    for (int k = 1; k < 8; ++k) mx = fmaxf(mx, v[k]);
    for (int o = 32; o > 0; o >>= 1) mx = fmaxf(mx, __shfl_down(mx, o, 64));
    if (lane == 0) red[wave] = mx;
    __syncthreads();
    if (tid == 0) bc = fmaxf(fmaxf(red[0], red[1]), fmaxf(red[2], red[3]));
    __syncthreads();
    float m = bc;
    float sum = 0.f;
    #pragma unroll
    for (int k = 0; k < 8; ++k) {
        int c = tid + k * 256;
        v[k] = (c < n) ? __expf(v[k] - m) : 0.f;
        sum += v[k];
    }
    for (int o = 32; o > 0; o >>= 1) sum += __shfl_down(sum, o, 64);
    __syncthreads();
    if (lane == 0) red[wave] = sum;
    __syncthreads();
    if (tid == 0) bc = 1.0f / (red[0] + red[1] + red[2] + red[3]);
    __syncthreads();
    float inv = bc;
    #pragma unroll
    for (int k = 0; k < 8; ++k) {
        int c = tid + k * 256;
        if (c < klim) row[c] = __float2bfloat16(c < n ? v[k] * inv : 0.f);
    }
}

// ---------------------------------------------------------------------------
static inline void gemm(hipStream_t st, const bf16* A, const bf16* BT, void* C,
                        const float* bias, const float* res,
                        int M, int N, int K, int lda, int ldb, int ldc,
                        long long sA, long long sB, long long sC,
                        int batch, int mode, int causal, int ksplit = 1, int kchunk = 0)
{
    if (kchunk == 0) kchunk = K;
    dim3 g((N + 127) / 128, M / 128, batch * ksplit);
    gemm_k<<<g, 256, 0, st>>>(A, BT, C, bias, res, M, N, K, lda, ldb, ldc,
                              sA, sB, sC, mode, causal, ksplit, kchunk);
}

static inline void gemm256(hipStream_t st, const bf16* A, const bf16* BT, void* C,
                           const float* bias, int M, int N, int K,
                           int lda, int ldb, int ldc, long long sC,
                           int mode, int ksplit = 1, int kchunk = 0)
{
    if (kchunk == 0) kchunk = K;
    dim3 g((N + 255) / 256, M / 256, ksplit);
    gemm256_k<<<g, 512, 0, st>>>(A, BT, C, bias, M, N, K, lda, ldb, ldc,
                                 sC, mode, kchunk);
}

static inline void transw(hipStream_t st, const float* in, bf16* out, int R, int C)
{
    dim3 g((C + 127) / 128, R / 32);
    transpose_w4<<<g, dim3(32, 8), 0, st>>>(in, out, R, C);
}

extern "C" void kernel_launch(void* const* d_in, const int* in_sizes, int n_in,
                              void* d_out, int out_size, void* d_ws, size_t ws_size,
                              hipStream_t stream)
{
    const float* x        = (const float*)d_in[0];
    const float* norm1_w  = (const float*)d_in[1];
    const float* q_a_w    = (const float*)d_in[2];
    const float* q_a_ln_w = (const float*)d_in[3];
    const float* q_b_w    = (const float*)d_in[4];
    const float* kv_a_w   = (const float*)d_in[5];
    const float* kv_a_ln_w= (const float*)d_in[6];
    const float* kv_b_w   = (const float*)d_in[7];
    const float* o_w      = (const float*)d_in[8];
    const float* norm2_w  = (const float*)d_in[9];
    const float* ffn_w1   = (const float*)d_in[10];
    const float* ffn_b1   = (const float*)d_in[11];
    const float* ffn_w2   = (const float*)d_in[12];
    const float* ffn_b2   = (const float*)d_in[13];
    float* out = (float*)d_out;

    // ---- workspace layout ----
    size_t off = 0;
    auto alloc = [&](size_t bytes) -> void* {
        void* p = (char*)d_ws + off;
        off += (bytes + 255) & ~(size_t)255;
        return p;
    };
    bf16*  hs     = (bf16*) alloc((size_t)S_*D_*2);                 //  8.4 MB
    bf16*  wqakvT = (bf16*) alloc((size_t)QKVN*D_*2);               //  8.7 MB
    bf16*  wqbT   = (bf16*) alloc((size_t)(H_*QKD_)*QR_*2);         //  9.4 MB
    bf16*  wkvbT  = (bf16*) alloc((size_t)(H_*(NOPE_+VD_))*KVR_*2); //  4.2 MB
    bf16*  woT    = (bf16*) alloc((size_t)D_*(H_*VD_)*2);           //  8.4 MB
    bf16*  wf1T   = (bf16*) alloc((size_t)(4*D_)*D_*2);             // 33.6 MB
    bf16*  wf2T   = (bf16*) alloc((size_t)D_*(4*D_)*2);             // 33.6 MB
    float* qakva32= (float*)alloc((size_t)S_*QKVN*4);               // 17.3 MB (x2 home)
    bf16*  qln    = (bf16*) alloc((size_t)S_*QR_*2);                //  6.3 MB
    bf16*  kvln   = (bf16*) alloc((size_t)S_*KVR_*2);               //  2.1 MB
    bf16*  qb     = (bf16*) alloc((size_t)S_*H_*QKD_*2);            // 12.6 MB (h2 home)
    bf16*  kvb    = (bf16*) alloc((size_t)S_*H_*(NOPE_+VD_)*2);     // 16.8 MB
    bf16*  qf     = (bf16*) alloc((size_t)H_*S_*QKD_*2);            // 12.6 MB
    bf16*  kf     = (bf16*) alloc((size_t)H_*S_*QKD_*2);            // 12.6 MB
    bf16*  vT     = (bf16*) alloc((size_t)H_*VD_*S_*2);             //  8.4 MB
    float* pe     = (float*)alloc((size_t)S_*ROPE_*4);              //  0.5 MB
    bf16*  Sc     = (bf16*) alloc((size_t)8*S_*S_*2);               // 67.1 MB
    // overlays (lifetimes disjoint):
    float* qakvaP = (float*)Sc;       // 3 x 17.3 MB in Sc            (pre-scores)
    float* qbP    = (float*)Sc;       // 2 x 25.2 MB in Sc            (pre-scores)
    float* pvP    = (float*)qakva32;  // 32 x 1.05 MB over qakva32+qln+kvln+qb
    float* oP     = (float*)Sc;       // 4 x 16.8 MB = 67.1 MB (Sc dead post-attn)
    float* f2P    = (float*)d_ws;     // 4 x 16.8 MB over hs..wf1T (dead at FFN2)
    float* x2     = qakva32;          // f32 residual, written post-attention
    bf16*  h2     = qb;               // post-attention rmsnorm output
    bf16*  ao     = kvb;              // attn out bf16 [S][2048]
    bf16*  a1     = Sc;               // ffn1 activation 33.6 MB (Sc dead post-attn)

    // ---- weight transposes (qa+kva fused along N) ----
    transw(stream, q_a_w,  wqakvT,                    D_,  QR_);
    transw(stream, kv_a_w, wqakvT + (size_t)QR_ * D_, D_,  KVR_+ROPE_);
    transw(stream, q_b_w,  wqbT,  QR_, H_*QKD_);
    transw(stream, kv_b_w, wkvbT, KVR_, H_*(NOPE_+VD_));
    transw(stream, o_w,    woT,   H_*VD_, D_);
    transw(stream, ffn_w1, wf1T,  D_,  4*D_);
    transw(stream, ffn_w2, wf2T,  4*D_, D_);

    // ---- pre-attention pipeline ----
    rmsnorm_k<<<S_, 256, 0, stream>>>(x, norm1_w, hs, D_, D_, D_);

    // fused qa+kva: 256^2 GEMM split-K 3 -> fused reduce+dual-rmsnorm+pe
    gemm256(stream, hs, wqakvT, qakvaP, nullptr, S_, QKVN, D_, D_, D_, QKVN,
            (long long)S_*QKVN, 6, 3, 768);
    red_qakva_k<<<S_, 256, 0, stream>>>(qakvaP, q_a_ln_w, kv_a_ln_w, qln, kvln, pe);

    // q_b GEMM split-K 2 -> fused reduce+build_q
    gemm256(stream, qln, wqbT, qbP, nullptr, S_, H_*QKD_, QR_, QR_, QR_, H_*QKD_,
            (long long)S_*(H_*QKD_), 6, 2, 768);
    red_buildq_k<<<S_, 256, 0, stream>>>(qbP, qf);

    gemm(stream, kvln, wkvbT, kvb, nullptr, nullptr, S_, H_*(NOPE_+VD_), KVR_,
         KVR_, KVR_, H_*(NOPE_+VD_), 0, 0, 0, 1, 1, 0);

    build_k<<<dim3(S_, H_), 192, 0, stream>>>(kvb, pe, kf);
    transpose_v<<<dim3(VD_/32, S_/32, H_), dim3(32, 8), 0, stream>>>(kvb, vT);

    // ---- attention: 2 groups of 8 heads; PV split-K 4 with partials ----
    for (int g = 0; g < 2; ++g) {
        const bf16* qfg = qf + (size_t)g * 8 * S_ * QKD_;
        const bf16* kfg = kf + (size_t)g * 8 * S_ * QKD_;
        const bf16* vTg = vT + (size_t)g * 8 * VD_ * S_;
        gemm(stream, qfg, kfg, Sc, nullptr, nullptr,
             S_, S_, QKD_, QKD_, QKD_, S_,
             (long long)S_*QKD_, (long long)S_*QKD_, (long long)S_*S_, 8, 1, 1);
        softmax_k<<<dim3(S_, 8), 256, 0, stream>>>(Sc);
        gemm(stream, Sc, vTg, pvP, nullptr, nullptr,
             S_, VD_, S_, S_, S_, VD_,
             (long long)S_*S_, (long long)VD_*S_, (long long)S_*VD_, 8, 6, 2, 4, 512);
        pv_red<<<dim3(S_, 8), 128, 0, stream>>>(pvP, ao, g);
    }

    // ---- o-projection: 256^2 split-K 4 -> fused reduce+residual+rmsnorm ----
    gemm256(stream, ao, woT, oP, nullptr, S_, D_, H_*VD_, H_*VD_, H_*VD_, D_,
            (long long)S_*D_, 6, 4, 512);
    red_o_rms_k<<<S_, 256, 0, stream>>>(oP, x, norm2_w, x2, h2);

    // ---- FFN ----
    gemm256(stream, h2, wf1T, a1, ffn_b1, S_, 4*D_, D_, D_, D_, 4*D_,
            0, 3, 1, 0);
    gemm256(stream, a1, wf2T, f2P, nullptr, S_, D_, 4*D_, 4*D_, 4*D_, D_,
            (long long)S_*D_, 6, 4, 2048);
    red_k<<<1024, 256, 0, stream>>>(f2P, (long long)S_*D_/4, 4, x2, ffn_b2, D_/4,
                                    out, nullptr, (long long)S_*D_/4);
}

// Round 12
// 877.803 us; speedup vs baseline: 1.3117x; 1.0309x over previous
//
#include <hip/hip_runtime.h>
#include <hip/hip_bf16.h>

typedef __hip_bfloat16 bf16;
using bf16x8 = __attribute__((ext_vector_type(8))) __bf16;
using f32x4  = __attribute__((ext_vector_type(4))) float;

#define S_   2048
#define D_   2048
#define H_   16
#define QR_  1536
#define KVR_ 512
#define NOPE_ 128
#define ROPE_ 64
#define VD_  128
#define QKD_ 192
#define EPS_ 1e-5f
#define QKVN 2112   // QR_ + KVR_ + ROPE_ (fused qa+kva output width)

// async global->LDS, 16B per lane; LDS dest = wave-uniform base + lane*16
#define GLDS16(g, l) \
    __builtin_amdgcn_global_load_lds((const __attribute__((address_space(1))) void*)(g), \
                                     (__attribute__((address_space(3))) void*)(l), 16, 0, 0)

#define PIPE_WAIT4 asm volatile("s_waitcnt vmcnt(4)\n\ts_barrier" ::: "memory")
#define PIPE_WAIT0 asm volatile("s_waitcnt vmcnt(0)\n\ts_barrier" ::: "memory")

__device__ __forceinline__ unsigned short bfbits(float f)
{
    bf16 t = __float2bfloat16(f);
    return *(unsigned short*)&t;
}

// ---------------------------------------------------------------------------
// bf16 MFMA GEMM (128x128 tile, 4 waves) — retained for causal scores / PV /
// small-K kv_b. 3-stage pipelined, vmcnt(4) barriers.
// mode: 0=f32, 1=bf16, 2=f32+res, 3=bf16 gelu(x+bias), 4=f32+bias+res, 6=f32 partial
// causal: 0 none, 1 skip upper tiles, 2 K limited to diagonal
// ---------------------------------------------------------------------------
__global__ __launch_bounds__(256) void gemm_k(
    const bf16* __restrict__ A, const bf16* __restrict__ BT, void* __restrict__ Cv,
    const float* __restrict__ bias, const float* __restrict__ res,
    int M, int N, int K, int lda, int ldb, int ldc,
    long long strideA, long long strideB, long long strideC,
    int mode, int causal, int ksplit, int kchunk)
{
    int bn = blockIdx.x, bm = blockIdx.y;
    int bzC = blockIdx.z;
    int bz = bzC, kc = 0;
    if (ksplit > 1) { kc = bzC % ksplit; bz = bzC / ksplit; }
    if (causal == 1 && bn > bm) return;
    A  += (size_t)bz * strideA;
    BT += (size_t)bz * strideB;

    int k_end = K;
    if (causal == 2) { int kl = (bm + 1) * 128; if (kl < k_end) k_end = kl; }
    int k_begin = kc * kchunk;
    if (k_begin + kchunk < k_end) k_end = k_begin + kchunk;
    if (k_begin >= k_end) return;
    int nIter = (k_end - k_begin) >> 5;

    __shared__ bf16 sA[3 * 128 * 32];
    __shared__ bf16 sB[3 * 128 * 32];

    int tid  = threadIdx.x;
    int lane = tid & 63, wave = tid >> 6;
    int wr = wave >> 1, wc = wave & 1;
    int fr = lane & 15, fq = lane >> 4;

    int row0 = bm * 128, col0 = bn * 128;

    int srow = wave * 16 + (lane >> 2);
    int sko  = (lane & 3) * 8;
    const bf16* ga0 = A + (size_t)(row0 + srow) * lda + sko;
    const bf16* ga1 = ga0 + (size_t)64 * lda;
    int bn0 = col0 + srow;      if (bn0 > N - 1) bn0 = N - 1;
    int bn1 = col0 + srow + 64; if (bn1 > N - 1) bn1 = N - 1;
    const bf16* gb0 = BT + (size_t)bn0 * ldb + sko;
    const bf16* gb1 = BT + (size_t)bn1 * ldb + sko;
    bf16* lA0 = &sA[(wave * 16) * 32];
    bf16* lA1 = &sA[(64 + wave * 16) * 32];
    bf16* lB0 = &sB[(wave * 16) * 32];
    bf16* lB1 = &sB[(64 + wave * 16) * 32];

#define STAGE(ofs, k0) do {                  \
        GLDS16(ga0 + (k0), lA0 + (ofs));     \
        GLDS16(ga1 + (k0), lA1 + (ofs));     \
        GLDS16(gb0 + (k0), lB0 + (ofs));     \
        GLDS16(gb1 + (k0), lB1 + (ofs));     \
    } while (0)

    f32x4 acc[4][4] = {};

#define COMPUTE(ofs) do {                                                           \
        bf16x8 af[4], bv[4];                                                        \
        _Pragma("unroll")                                                           \
        for (int i = 0; i < 4; ++i)                                                 \
            af[i] = *(const bf16x8*)&sA[(ofs) + (wr*64 + i*16 + fr)*32 + fq*8];     \
        _Pragma("unroll")                                                           \
        for (int j = 0; j < 4; ++j)                                                 \
            bv[j] = *(const bf16x8*)&sB[(ofs) + (wc*64 + j*16 + fr)*32 + fq*8];     \
        _Pragma("unroll")                                                           \
        for (int i = 0; i < 4; ++i)                                                 \
            _Pragma("unroll")                                                       \
            for (int j = 0; j < 4; ++j)                                             \
                acc[i][j] = __builtin_amdgcn_mfma_f32_16x16x32_bf16(af[i], bv[j], acc[i][j], 0, 0, 0); \
    } while (0)

    STAGE(0, k_begin);
    if (nIter > 1) STAGE(4096, k_begin + 32);

    int curo = 0, pfo = 8192;
    int it = 0;
    for (; it < nIter - 1; ++it) {
        PIPE_WAIT4;
        if (it + 2 < nIter) STAGE(pfo, k_begin + (it + 2) * 32);
        COMPUTE(curo);
        curo += 4096; if (curo == 12288) curo = 0;
        pfo  += 4096; if (pfo  == 12288) pfo  = 0;
    }
    PIPE_WAIT0;
    COMPUTE(curo);
#undef STAGE
#undef COMPUTE

    #pragma unroll
    for (int i = 0; i < 4; ++i) {
        #pragma unroll
        for (int j = 0; j < 4; ++j) {
            int gc = col0 + wc*64 + j*16 + fr;
            if (gc >= N) continue;
            #pragma unroll
            for (int r = 0; r < 4; ++r) {
                int gr = row0 + wr*64 + i*16 + fq*4 + r;
                float v = acc[i][j][r];
                size_t off = (size_t)bzC * strideC + (size_t)gr * ldc + gc;
                if (mode == 0 || mode == 6) {
                    ((float*)Cv)[off] = v;
                } else if (mode == 1) {
                    ((bf16*)Cv)[off] = __float2bfloat16(v);
                } else if (mode == 2) {
                    ((float*)Cv)[off] = v + res[(size_t)gr * ldc + gc];
                } else if (mode == 3) {
                    float t = v + bias[gc];
                    t = 0.5f * t * (1.0f + erff(t * 0.70710678118654752f));
                    ((bf16*)Cv)[off] = __float2bfloat16(t);
                } else {
                    ((float*)Cv)[off] = v + bias[gc] + res[(size_t)gr * ldc + gc];
                }
            }
        }
    }
}

// ---------------------------------------------------------------------------
// 256x256-tile, 8-wave, 8-phase bf16 GEMM (R2-verified variant).
//  - BK=64, double-buffered LDS (128 KiB), one K-tile per buffer.
//  - chunk-XOR swizzle: LDS dest linear (global_load_lds), SOURCE pre-swizzled,
//    ds_read applies the same involution -> conflict-free (verified 0).
//  - per tile: ph1 reads A-lo+all B + stages A1(t+1); ph2 reads A-hi,
//    stages B0(t+2); ph3 stages B1(t+2); ph4 stages A0(t+2) + vmcnt(6).
// mode: 0=f32, 1=bf16, 3=bf16 gelu(x+bias), 6=f32 partial (plane = blockIdx.z)
// ---------------------------------------------------------------------------
__global__ __launch_bounds__(512, 2) void gemm256_k(
    const bf16* __restrict__ A, const bf16* __restrict__ BT, void* __restrict__ Cv,
    const float* __restrict__ bias,
    int M, int N, int K, int lda, int ldb, int ldc,
    long long strideC, int mode, int kchunk)
{
    int bn = blockIdx.x, bm = blockIdx.y, kc = blockIdx.z;
    int k_begin = kc * kchunk;
    int k_end = (k_begin + kchunk < K) ? (k_begin + kchunk) : K;
    int NT = (k_end - k_begin) >> 6;

    __shared__ __align__(16) bf16 sA[2 * 256 * 64];   // 64 KiB
    __shared__ __align__(16) bf16 sB[2 * 256 * 64];   // 64 KiB

    int tid = threadIdx.x;
    int lane = tid & 63, w = tid >> 6;
    int wr = w >> 2, wc = w & 3;            // 2x4 wave grid; wave owns 128x64
    int fr = lane & 15, fq = lane >> 4;
    int row0 = bm * 256, col0 = bn * 256;

    int g0 = tid, g1 = tid + 512;
    int r0 = g0 >> 3, l0 = (g0 & 7) ^ (r0 & 7);
    int r1 = g1 >> 3, l1 = (g1 & 7) ^ (r1 & 7);
    const bf16* gA00 = A + (size_t)(row0 + r0) * lda + k_begin + l0 * 8;
    const bf16* gA01 = A + (size_t)(row0 + r1) * lda + k_begin + l1 * 8;
    const bf16* gA10 = gA00 + (size_t)128 * lda;
    const bf16* gA11 = gA01 + (size_t)128 * lda;
    int c00 = col0 + r0;       if (c00 > N - 1) c00 = N - 1;
    int c01 = col0 + r1;       if (c01 > N - 1) c01 = N - 1;
    int c10 = col0 + 128 + r0; if (c10 > N - 1) c10 = N - 1;
    int c11 = col0 + 128 + r1; if (c11 > N - 1) c11 = N - 1;
    const bf16* gB00 = BT + (size_t)c00 * ldb + k_begin + l0 * 8;
    const bf16* gB01 = BT + (size_t)c01 * ldb + k_begin + l1 * 8;
    const bf16* gB10 = BT + (size_t)c10 * ldb + k_begin + l0 * 8;
    const bf16* gB11 = BT + (size_t)c11 * ldb + k_begin + l1 * 8;

#define ST_HALF(arr, bofs, p0, p1, t) do {                                  \
        GLDS16((p0) + (size_t)(t) * 64, (arr) + (bofs) + w * 512);          \
        GLDS16((p1) + (size_t)(t) * 64, (arr) + (bofs) + w * 512 + 4096);   \
    } while (0)
#define ST_A0(b, t) ST_HALF(sA, (b) * 16384,        gA00, gA01, t)
#define ST_A1(b, t) ST_HALF(sA, (b) * 16384 + 8192, gA10, gA11, t)
#define ST_B0(b, t) ST_HALF(sB, (b) * 16384,        gB00, gB01, t)
#define ST_B1(b, t) ST_HALF(sB, (b) * 16384 + 8192, gB10, gB11, t)

    int arow = (wr * 128 + fr) * 64;
    int brow = (wc * 64 + fr) * 64;
    int pk0 = (fq ^ (fr & 7)) * 8;
    int pk1 = pk0 ^ 32;

    f32x4 acc[8][4] = {};

#define MFMA_QUAD(AF, IOFF, N0) do {                                        \
        __builtin_amdgcn_s_setprio(1);                                      \
        _Pragma("unroll")                                                   \
        for (int m = 0; m < 4; ++m) {                                       \
            _Pragma("unroll")                                               \
            for (int n = 0; n < 2; ++n) {                                   \
                acc[(IOFF)+m][(N0)+n] = __builtin_amdgcn_mfma_f32_16x16x32_bf16( \
                    AF[m][0], bfr[(N0)+n][0], acc[(IOFF)+m][(N0)+n], 0, 0, 0);   \
                acc[(IOFF)+m][(N0)+n] = __builtin_amdgcn_mfma_f32_16x16x32_bf16( \
                    AF[m][1], bfr[(N0)+n][1], acc[(IOFF)+m][(N0)+n], 0, 0, 0);   \
            }                                                               \
        }                                                                   \
        __builtin_amdgcn_s_setprio(0);                                      \
    } while (0)

    ST_A0(0, 0); ST_A1(0, 0); ST_B0(0, 0); ST_B1(0, 0);
    if (NT > 1) { ST_B0(1, 1); ST_B1(1, 1); ST_A0(1, 1); }
    if (NT > 1) asm volatile("s_waitcnt vmcnt(6)" ::: "memory");
    else        asm volatile("s_waitcnt vmcnt(0)" ::: "memory");
    __builtin_amdgcn_s_barrier();

    for (int t = 0; t < NT; ++t) {
        int buf = t & 1;
        int sbase = buf * 16384;
        bf16x8 aflo[4][2], afhi[4][2], bfr[4][2];

        // ---- phase 1: read A m0-3 (8) + B n0-3 (8); stage A1(t+1) ----
        #pragma unroll
        for (int m = 0; m < 4; ++m) {
            aflo[m][0] = *(const bf16x8*)&sA[sbase + arow + m*1024 + pk0];
            aflo[m][1] = *(const bf16x8*)&sA[sbase + arow + m*1024 + pk1];
        }
        #pragma unroll
        for (int n = 0; n < 4; ++n) {
            bfr[n][0] = *(const bf16x8*)&sB[sbase + brow + n*1024 + pk0];
            bfr[n][1] = *(const bf16x8*)&sB[sbase + brow + n*1024 + pk1];
        }
        if (t + 1 < NT) ST_A1((t + 1) & 1, t + 1);
        asm volatile("s_waitcnt lgkmcnt(8)" ::: "memory");
        __builtin_amdgcn_s_barrier();
        asm volatile("s_waitcnt lgkmcnt(0)" ::: "memory");
        __builtin_amdgcn_sched_barrier(0);
        MFMA_QUAD(aflo, 0, 0);
        __builtin_amdgcn_s_barrier();

        // ---- phase 2: read A m4-7 (8); stage B0(t+2) ----
        #pragma unroll
        for (int m = 0; m < 4; ++m) {
            afhi[m][0] = *(const bf16x8*)&sA[sbase + arow + 4096 + m*1024 + pk0];
            afhi[m][1] = *(const bf16x8*)&sA[sbase + arow + 4096 + m*1024 + pk1];
        }
        if (t + 2 < NT) ST_B0(buf, t + 2);
        __builtin_amdgcn_s_barrier();
        asm volatile("s_waitcnt lgkmcnt(0)" ::: "memory");
        __builtin_amdgcn_sched_barrier(0);
        MFMA_QUAD(aflo, 0, 2);
        __builtin_amdgcn_s_barrier();

        // ---- phase 3: stage B1(t+2); MFMA hi x lo ----
        if (t + 2 < NT) ST_B1(buf, t + 2);
        __builtin_amdgcn_s_barrier();
        asm volatile("s_waitcnt lgkmcnt(0)" ::: "memory");
        __builtin_amdgcn_sched_barrier(0);
        MFMA_QUAD(afhi, 4, 0);
        __builtin_amdgcn_s_barrier();

        // ---- phase 4: stage A0(t+2); counted vmcnt; MFMA hi x hi ----
        if (t + 2 < NT) ST_A0(buf, t + 2);
        if (t < NT - 2) asm volatile("s_waitcnt vmcnt(6)" ::: "memory");
        else            asm volatile("s_waitcnt vmcnt(0)" ::: "memory");
        __builtin_amdgcn_s_barrier();
        MFMA_QUAD(afhi, 4, 2);
        __builtin_amdgcn_s_barrier();
    }
#undef MFMA_QUAD
#undef ST_A0
#undef ST_A1
#undef ST_B0
#undef ST_B1
#undef ST_HALF

    #pragma unroll
    for (int i = 0; i < 8; ++i) {
        #pragma unroll
        for (int j = 0; j < 4; ++j) {
            int gc = col0 + wc*64 + j*16 + fr;
            if (gc >= N) continue;
            #pragma unroll
            for (int r = 0; r < 4; ++r) {
                int gr = row0 + wr*128 + i*16 + fq*4 + r;
                float v = acc[i][j][r];
                size_t off = (size_t)kc * strideC + (size_t)gr * ldc + gc;
                if (mode == 0 || mode == 6) {
                    ((float*)Cv)[off] = v;
                } else if (mode == 1) {
                    ((bf16*)Cv)[off] = __float2bfloat16(v);
                } else {  // mode 3: gelu(x + bias) -> bf16
                    float tt = v + bias[gc];
                    tt = 0.5f * tt * (1.0f + erff(tt * 0.70710678118654752f));
                    ((bf16*)Cv)[off] = __float2bfloat16(tt);
                }
            }
        }
    }
}

// ---------------------------------------------------------------------------
// Split-K reduce: dst = sum of nch partial planes (+res)(+bias), float4.
// ---------------------------------------------------------------------------
__global__ __launch_bounds__(256) void red_k(const float* __restrict__ part,
        long long pstride4, int nch, const float* __restrict__ res,
        const float* __restrict__ bias, long long cols4,
        float* __restrict__ dstF, bf16* __restrict__ dstB, long long n4)
{
    long long i = (long long)blockIdx.x * 256 + threadIdx.x;
    long long stride = (long long)gridDim.x * 256;
    for (; i < n4; i += stride) {
        float4 v = ((const float4*)part)[i];
        for (int k = 1; k < nch; ++k) {
            float4 p = ((const float4*)part)[i + k * pstride4];
            v.x += p.x; v.y += p.y; v.z += p.z; v.w += p.w;
        }
        if (res) {
            float4 rr = ((const float4*)res)[i];
            v.x += rr.x; v.y += rr.y; v.z += rr.z; v.w += rr.w;
        }
        if (bias) {
            float4 b = ((const float4*)bias)[i % cols4];
            v.x += b.x; v.y += b.y; v.z += b.z; v.w += b.w;
        }
        if (dstB) {
            ushort4 o;
            o.x = bfbits(v.x); o.y = bfbits(v.y);
            o.z = bfbits(v.z); o.w = bfbits(v.w);
            ((ushort4*)dstB)[i] = o;
        } else {
            ((float4*)dstF)[i] = v;
        }
    }
}

// ---------------------------------------------------------------------------
// Fused: qakva split-K(3) reduce + rmsnorm(q_a_ln) + rmsnorm(kv_a_ln) + pe.
// One block per row s. part = [3][S][QKVN] f32. float4 path (all segment
// boundaries are multiples of 4: 1536, 2048, 2112).
// ---------------------------------------------------------------------------
__global__ __launch_bounds__(256) void red_qakva_k(const float* __restrict__ part,
        const float* __restrict__ qw, const float* __restrict__ kvw,
        bf16* __restrict__ qln, bf16* __restrict__ kvln, float* __restrict__ pe)
{
    int row = blockIdx.x, tid = threadIdx.x;
    const float4* p0 = (const float4*)(part + (size_t)row * QKVN);
    const float4* p1 = (const float4*)(part + (size_t)(S_ + row) * QKVN);
    const float4* p2 = (const float4*)(part + (size_t)(2 * S_ + row) * QKVN);
    float4 v[3];
    float ssq_q = 0.f, ssq_kv = 0.f;
    #pragma unroll
    for (int k = 0; k < 3; ++k) {
        int c4 = tid + k * 256;
        float4 s = make_float4(0.f, 0.f, 0.f, 0.f);
        if (c4 < QKVN / 4) {
            float4 a = p0[c4], b = p1[c4], c = p2[c4];
            s.x = a.x + b.x + c.x; s.y = a.y + b.y + c.y;
            s.z = a.z + b.z + c.z; s.w = a.w + b.w + c.w;
        }
        v[k] = s;
        int c = c4 * 4;
        float d = s.x*s.x + s.y*s.y + s.z*s.z + s.w*s.w;
        if (c < QR_) ssq_q += d;
        else if (c < QR_ + KVR_) ssq_kv += d;
    }
    for (int o = 32; o > 0; o >>= 1) {
        ssq_q  += __shfl_down(ssq_q,  o, 64);
        ssq_kv += __shfl_down(ssq_kv, o, 64);
    }
    __shared__ float rq[4], rkv[4];
    __shared__ float sq, skv;
    int wave = tid >> 6, lane = tid & 63;
    if (lane == 0) { rq[wave] = ssq_q; rkv[wave] = ssq_kv; }
    __syncthreads();
    if (tid == 0) {
        sq  = rsqrtf((rq[0]+rq[1]+rq[2]+rq[3])   / (float)QR_  + EPS_);
        skv = rsqrtf((rkv[0]+rkv[1]+rkv[2]+rkv[3]) / (float)KVR_ + EPS_);
    }
    __syncthreads();
    float a = sq, b = skv;
    #pragma unroll
    for (int k = 0; k < 3; ++k) {
        int c4 = tid + k * 256;
        if (c4 >= QKVN / 4) continue;
        int c = c4 * 4;
        float4 s = v[k];
        if (c < QR_) {
            float4 w4 = ((const float4*)qw)[c4];
            ushort4 o;
            o.x = bfbits(s.x * a * w4.x); o.y = bfbits(s.y * a * w4.y);
            o.z = bfbits(s.z * a * w4.z); o.w = bfbits(s.w * a * w4.w);
            *(ushort4*)&qln[(size_t)row * QR_ + c] = o;
        } else if (c < QR_ + KVR_) {
            int cc = c - QR_;
            float4 w4 = ((const float4*)kvw)[cc >> 2];
            ushort4 o;
            o.x = bfbits(s.x * b * w4.x); o.y = bfbits(s.y * b * w4.y);
            o.z = bfbits(s.z * b * w4.z); o.w = bfbits(s.w * b * w4.w);
            *(ushort4*)&kvln[(size_t)row * KVR_ + cc] = o;
        } else {
            ((float4*)(pe + (size_t)row * ROPE_))[(c - QR_ - KVR_) >> 2] = s;
        }
    }
}

#define ROPE_LC 0.28782313662425575f

// ---------------------------------------------------------------------------
// Fused: qb split-K(2) reduce + build_q (scale nope, rope pe) -> qf[h][s][d].
// One block per row s. part = [2][S][H*QKD] f32. float4 rowv fill.
// ---------------------------------------------------------------------------
__global__ __launch_bounds__(256) void red_buildq_k(const float* __restrict__ part,
                                                    bf16* __restrict__ qf)
{
    int s = blockIdx.x, tid = threadIdx.x;
    const float4* p0 = (const float4*)(part + (size_t)s * (H_*QKD_));
    const float4* p1 = (const float4*)(part + (size_t)(S_ + s) * (H_*QKD_));
    __shared__ __align__(16) float rowv[H_*QKD_];   // 3072 f32 = 12 KB
    #pragma unroll
    for (int k = 0; k < 3; ++k) {
        int c4 = tid + k * 256;
        float4 a = p0[c4], b = p1[c4];
        float4 r;
        r.x = a.x + b.x; r.y = a.y + b.y; r.z = a.z + b.z; r.w = a.w + b.w;
        ((float4*)rowv)[c4] = r;
    }
    __syncthreads();
    const float scale = 0.07216878364870323f;  // 1/sqrt(192)
    for (int o = tid; o < H_*QKD_; o += 256) {
        int h = o / QKD_, t = o - h*QKD_;
        const float* src = rowv + h*QKD_;
        float outv;
        if (t < NOPE_) {
            outv = src[t] * scale;
        } else {
            int i = (t - NOPE_) & 31;
            bool hi = (t - NOPE_) >= 32;
            float a = src[NOPE_ + 2*i], b = src[NOPE_ + 2*i + 1];
            float inv = __expf(-(float)i * ROPE_LC);
            float f = (float)s * inv, c2, sn;
            sincosf(f, &sn, &c2);
            outv = (hi ? (b * c2 + a * sn) : (a * c2 - b * sn)) * scale;
        }
        qf[((size_t)h * S_ + s) * QKD_ + t] = __float2bfloat16(outv);
    }
}

// ---------------------------------------------------------------------------
// Fused: o-proj split-K(4) reduce + residual add + rmsnorm(norm2) -> x2, h2.
// One block per row. part = [4][S][D] f32. float4 path.
// ---------------------------------------------------------------------------
__global__ __launch_bounds__(256) void red_o_rms_k(const float* __restrict__ part,
        const float* __restrict__ x, const float* __restrict__ w,
        float* __restrict__ x2, bf16* __restrict__ h2)
{
    int row = blockIdx.x, tid = threadIdx.x;
    const float4* p  = (const float4*)part + (size_t)row * (D_/4);
    const float4* x4 = (const float4*)x   + (size_t)row * (D_/4);
    float4*       o4 = (float4*)x2        + (size_t)row * (D_/4);
    const long long pl4 = (long long)S_ * (D_/4);
    float4 v[2];
    float ssq = 0.f;
    #pragma unroll
    for (int k = 0; k < 2; ++k) {
        int c4 = tid + k * 256;
        float4 s = p[c4];
        float4 q1 = p[c4 + pl4], q2 = p[c4 + 2*pl4], q3 = p[c4 + 3*pl4], xr = x4[c4];
        s.x += q1.x + q2.x + q3.x + xr.x;
        s.y += q1.y + q2.y + q3.y + xr.y;
        s.z += q1.z + q2.z + q3.z + xr.z;
        s.w += q1.w + q2.w + q3.w + xr.w;
        v[k] = s;
        ssq += s.x*s.x + s.y*s.y + s.z*s.z + s.w*s.w;
        o4[c4] = s;
    }
    for (int o = 32; o > 0; o >>= 1) ssq += __shfl_down(ssq, o, 64);
    __shared__ float red[4];
    __shared__ float s_sc;
    int wave = tid >> 6, lane = tid & 63;
    if (lane == 0) red[wave] = ssq;
    __syncthreads();
    if (tid == 0) s_sc = rsqrtf((red[0]+red[1]+red[2]+red[3]) / (float)D_ + EPS_);
    __syncthreads();
    float sc = s_sc;
    #pragma unroll
    for (int k = 0; k < 2; ++k) {
        int c4 = tid + k * 256;
        float4 s = v[k];
        float4 w4 = ((const float4*)w)[c4];
        ushort4 o;
        o.x = bfbits(s.x * sc * w4.x); o.y = bfbits(s.y * sc * w4.y);
        o.z = bfbits(s.z * sc * w4.z); o.w = bfbits(s.w * sc * w4.w);
        *(ushort4*)&h2[(size_t)row * D_ + c4 * 4] = o;
    }
}

// PV split-K reduce with causal chunk-validity: part[head][4][S][128] (kchunk=512)
// float4 per thread, 32 threads.
__global__ __launch_bounds__(32) void pv_red(const float* __restrict__ part,
                                             bf16* __restrict__ ao, int grp)
{
    int r = blockIdx.x, head = blockIdx.y, d4 = threadIdx.x;   // 0..31
    int nv = ((r >> 7) + 4) >> 2;
    const float4* p = (const float4*)(part + ((size_t)head * 4) * S_ * VD_
                                           + (size_t)r * VD_) + d4;
    float4 s = make_float4(0.f, 0.f, 0.f, 0.f);
    for (int k = 0; k < nv; ++k) {
        float4 t = p[(size_t)k * (S_ * VD_ / 4)];
        s.x += t.x; s.y += t.y; s.z += t.z; s.w += t.w;
    }
    ushort4 o;
    o.x = bfbits(s.x); o.y = bfbits(s.y); o.z = bfbits(s.z); o.w = bfbits(s.w);
    *(ushort4*)&ao[(size_t)r * (H_ * VD_) + grp * 1024 + head * VD_ + d4 * 4] = o;
}

// ---------------------------------------------------------------------------
// Vectorized weight transpose + f32->bf16: in[R,C] f32 -> out[C,R] bf16.
// 32-row x 128-col tiles; float4 reads; R must be a multiple of 32.
// ---------------------------------------------------------------------------
__global__ __launch_bounds__(256) void transpose_w4(const float* __restrict__ in,
                                                    bf16* __restrict__ out, int R, int C)
{
    __shared__ float t[128][33];
    int c0 = blockIdx.x * 128, r0 = blockIdx.y * 32;
    int tx = threadIdx.x, ty = threadIdx.y;   // (32, 8)
    #pragma unroll
    for (int j = 0; j < 4; ++j) {
        int r = r0 + ty + j*8;
        int c = c0 + tx*4;
        if (c + 3 < C) {
            float4 v4 = *(const float4*)&in[(size_t)r * C + c];
            t[tx*4+0][ty+j*8] = v4.x; t[tx*4+1][ty+j*8] = v4.y;
            t[tx*4+2][ty+j*8] = v4.z; t[tx*4+3][ty+j*8] = v4.w;
        } else {
            #pragma unroll
            for (int kk = 0; kk < 4; ++kk) {
                int cc = c + kk;
                t[tx*4+kk][ty+j*8] = (cc < C) ? in[(size_t)r * C + cc] : 0.f;
            }
        }
    }
    __syncthreads();
    #pragma unroll
    for (int j = 0; j < 16; ++j) {
        int cl = ty + j*8;
        int c = c0 + cl;
        if (c < C) out[(size_t)c * R + r0 + tx] = __float2bfloat16(t[cl][tx]);
    }
}

// vT[h][d][s] = kv[s][h*256 + 128 + d]
__global__ __launch_bounds__(256) void transpose_v(const bf16* __restrict__ kv,
                                                   bf16* __restrict__ vT)
{
    __shared__ bf16 t[32][33];
    int h = blockIdx.z;
    int d0 = blockIdx.x * 32, s0 = blockIdx.y * 32;
    int tx = threadIdx.x, ty = threadIdx.y;
    for (int j = ty; j < 32; j += 8)
        t[j][tx] = kv[(size_t)(s0 + j) * (H_*256) + h*256 + 128 + d0 + tx];
    __syncthreads();
    for (int j = ty; j < 32; j += 8)
        vT[((size_t)h * VD_ + d0 + j) * S_ + s0 + tx] = t[tx][j];
}

// ---------------------------------------------------------------------------
// RMSNorm: f32 in (strided) -> bf16 out
// ---------------------------------------------------------------------------
__global__ __launch_bounds__(256) void rmsnorm_k(const float* __restrict__ in,
                                                 const float* __restrict__ w,
                                                 bf16* __restrict__ out,
                                                 int cols, int istride, int ostride)
{
    int row = blockIdx.x, tid = threadIdx.x;
    const float* ip = in + (size_t)row * istride;
    bf16* op = out + (size_t)row * ostride;
    float ss = 0.f;
    for (int c = tid; c < cols; c += 256) { float v = ip[c]; ss = fmaf(v, v, ss); }
    for (int o = 32; o > 0; o >>= 1) ss += __shfl_down(ss, o, 64);
    __shared__ float red[4];
    __shared__ float s_sc;
    int wave = tid >> 6, lane = tid & 63;
    if (lane == 0) red[wave] = ss;
    __syncthreads();
    if (tid == 0) s_sc = rsqrtf((red[0]+red[1]+red[2]+red[3]) / (float)cols + EPS_);
    __syncthreads();
    float sc = s_sc;
    for (int c = tid; c < cols; c += 256)
        op[c] = __float2bfloat16(ip[c] * sc * w[c]);
}

// kf: nope from kv[s][h*256+d]; roped pe from pe[s][0..63]
__global__ __launch_bounds__(192) void build_k(const bf16* __restrict__ kv,
                                               const float* __restrict__ pe,
                                               bf16* __restrict__ kf)
{
    int s = blockIdx.x, h = blockIdx.y, t = threadIdx.x;
    const bf16* src = kv + (size_t)s * (H_*256) + h * 256;
    bf16* dst = kf + ((size_t)h * S_ + s) * QKD_;
    if (t < NOPE_) {
        dst[t] = src[t];
    } else {
        int i = (t - NOPE_) & 31;
        bool hi = (t - NOPE_) >= 32;
        const float* p = pe + (size_t)s * ROPE_;
        float a = p[2*i], b = p[2*i + 1];
        float inv = __expf(-(float)i * ROPE_LC);
        float f = (float)s * inv, c, sn;
        sincosf(f, &sn, &c);
        dst[t] = __float2bfloat16(hi ? (b * c + a * sn) : (a * c - b * sn));
    }
}

// ---------------------------------------------------------------------------
// Causal softmax — vectorized: one uint4 (8 bf16) load/store per thread.
// Thread t owns columns [t*8, t*8+8); zero-pads to 128 boundary.
// ---------------------------------------------------------------------------
__global__ __launch_bounds__(256) void softmax_k(bf16* __restrict__ Sc)
{
    int q = blockIdx.x, h = blockIdx.y;
    bf16* row = Sc + ((size_t)h * S_ + q) * S_;
    int n = q + 1;
    int klim = ((q >> 7) + 1) << 7;
    int tid = threadIdx.x, lane = tid & 63, wave = tid >> 6;
    __shared__ float red[4];
    __shared__ float bc;

    int c0 = tid * 8;
    uint4 u = *(const uint4*)&row[c0];
    unsigned uw[4] = {u.x, u.y, u.z, u.w};
    float v[8];
    #pragma unroll
    for (int j = 0; j < 8; ++j) {
        unsigned bits = (j & 1) ? (uw[j >> 1] & 0xffff0000u) : (uw[j >> 1] << 16);
        float f = __uint_as_float(bits);
        v[j] = (c0 + j < n) ? f : -3.0e38f;
    }
    float mx = v[0];
    #pragma unroll
    for (int j = 1; j < 8; ++j) mx = fmaxf(mx, v[j]);
    for (int o = 32; o > 0; o >>= 1) mx = fmaxf(mx, __shfl_down(mx, o, 64));
    if (lane == 0) red[wave] = mx;
    __syncthreads();
    if (tid == 0) bc = fmaxf(fmaxf(red[0], red[1]), fmaxf(red[2], red[3]));
    __syncthreads();
    float m = bc;
    float sum = 0.f;
    #pragma unroll
    for (int j = 0; j < 8; ++j) {
        v[j] = (c0 + j < n) ? __expf(v[j] - m) : 0.f;
        sum += v[j];
    }
    for (int o = 32; o > 0; o >>= 1) sum += __shfl_down(sum, o, 64);
    __syncthreads();
    if (lane == 0) red[wave] = sum;
    __syncthreads();
    if (tid == 0) bc = 1.0f / (red[0] + red[1] + red[2] + red[3]);
    __syncthreads();
    float inv = bc;
    if (c0 < klim) {
        unsigned o[4];
        #pragma unroll
        for (int j2 = 0; j2 < 4; ++j2) {
            unsigned lo = bfbits(v[2*j2]     * inv);
            unsigned hi = bfbits(v[2*j2 + 1] * inv);
            o[j2] = lo | (hi << 16);
        }
        *(uint4*)&row[c0] = make_uint4(o[0], o[1], o[2], o[3]);
    }
}

// ---------------------------------------------------------------------------
static inline void gemm(hipStream_t st, const bf16* A, const bf16* BT, void* C,
                        const float* bias, const float* res,
                        int M, int N, int K, int lda, int ldb, int ldc,
                        long long sA, long long sB, long long sC,
                        int batch, int mode, int causal, int ksplit = 1, int kchunk = 0)
{
    if (kchunk == 0) kchunk = K;
    dim3 g((N + 127) / 128, M / 128, batch * ksplit);
    gemm_k<<<g, 256, 0, st>>>(A, BT, C, bias, res, M, N, K, lda, ldb, ldc,
                              sA, sB, sC, mode, causal, ksplit, kchunk);
}

static inline void gemm256(hipStream_t st, const bf16* A, const bf16* BT, void* C,
                           const float* bias, int M, int N, int K,
                           int lda, int ldb, int ldc, long long sC,
                           int mode, int ksplit = 1, int kchunk = 0)
{
    if (kchunk == 0) kchunk = K;
    dim3 g((N + 255) / 256, M / 256, ksplit);
    gemm256_k<<<g, 512, 0, st>>>(A, BT, C, bias, M, N, K, lda, ldb, ldc,
                                 sC, mode, kchunk);
}

static inline void transw(hipStream_t st, const float* in, bf16* out, int R, int C)
{
    dim3 g((C + 127) / 128, R / 32);
    transpose_w4<<<g, dim3(32, 8), 0, st>>>(in, out, R, C);
}

extern "C" void kernel_launch(void* const* d_in, const int* in_sizes, int n_in,
                              void* d_out, int out_size, void* d_ws, size_t ws_size,
                              hipStream_t stream)
{
    const float* x        = (const float*)d_in[0];
    const float* norm1_w  = (const float*)d_in[1];
    const float* q_a_w    = (const float*)d_in[2];
    const float* q_a_ln_w = (const float*)d_in[3];
    const float* q_b_w    = (const float*)d_in[4];
    const float* kv_a_w   = (const float*)d_in[5];
    const float* kv_a_ln_w= (const float*)d_in[6];
    const float* kv_b_w   = (const float*)d_in[7];
    const float* o_w      = (const float*)d_in[8];
    const float* norm2_w  = (const float*)d_in[9];
    const float* ffn_w1   = (const float*)d_in[10];
    const float* ffn_b1   = (const float*)d_in[11];
    const float* ffn_w2   = (const float*)d_in[12];
    const float* ffn_b2   = (const float*)d_in[13];
    float* out = (float*)d_out;

    // ---- workspace layout ----
    size_t off = 0;
    auto alloc = [&](size_t bytes) -> void* {
        void* p = (char*)d_ws + off;
        off += (bytes + 255) & ~(size_t)255;
        return p;
    };
    bf16*  hs     = (bf16*) alloc((size_t)S_*D_*2);                 //  8.4 MB
    bf16*  wqakvT = (bf16*) alloc((size_t)QKVN*D_*2);               //  8.7 MB
    bf16*  wqbT   = (bf16*) alloc((size_t)(H_*QKD_)*QR_*2);         //  9.4 MB
    bf16*  wkvbT  = (bf16*) alloc((size_t)(H_*(NOPE_+VD_))*KVR_*2); //  4.2 MB
    bf16*  woT    = (bf16*) alloc((size_t)D_*(H_*VD_)*2);           //  8.4 MB
    bf16*  wf1T   = (bf16*) alloc((size_t)(4*D_)*D_*2);             // 33.6 MB
    bf16*  wf2T   = (bf16*) alloc((size_t)D_*(4*D_)*2);             // 33.6 MB
    float* qakva32= (float*)alloc((size_t)S_*QKVN*4);               // 17.3 MB (x2 home)
    bf16*  qln    = (bf16*) alloc((size_t)S_*QR_*2);                //  6.3 MB
    bf16*  kvln   = (bf16*) alloc((size_t)S_*KVR_*2);               //  2.1 MB
    bf16*  qb     = (bf16*) alloc((size_t)S_*H_*QKD_*2);            // 12.6 MB (h2 home)
    bf16*  kvb    = (bf16*) alloc((size_t)S_*H_*(NOPE_+VD_)*2);     // 16.8 MB
    bf16*  qf     = (bf16*) alloc((size_t)H_*S_*QKD_*2);            // 12.6 MB
    bf16*  kf     = (bf16*) alloc((size_t)H_*S_*QKD_*2);            // 12.6 MB
    bf16*  vT     = (bf16*) alloc((size_t)H_*VD_*S_*2);             //  8.4 MB
    float* pe     = (float*)alloc((size_t)S_*ROPE_*4);              //  0.5 MB
    bf16*  Sc     = (bf16*) alloc((size_t)8*S_*S_*2);               // 67.1 MB
    // overlays (lifetimes disjoint):
    float* qakvaP = (float*)Sc;       // 3 x 17.3 MB in Sc            (pre-scores)
    float* qbP    = (float*)Sc;       // 2 x 25.2 MB in Sc            (pre-scores)
    float* pvP    = (float*)qakva32;  // 32 x 1.05 MB over qakva32+qln+kvln+qb
    float* oP     = (float*)Sc;       // 4 x 16.8 MB = 67.1 MB (Sc dead post-attn)
    float* f2P    = (float*)d_ws;     // 4 x 16.8 MB over hs..wf1T (dead at FFN2)
    float* x2     = qakva32;          // f32 residual, written post-attention
    bf16*  h2     = qb;               // post-attention rmsnorm output
    bf16*  ao     = kvb;              // attn out bf16 [S][2048]
    bf16*  a1     = Sc;               // ffn1 activation 33.6 MB (Sc dead post-attn)

    // ---- weight transposes (qa+kva fused along N) ----
    transw(stream, q_a_w,  wqakvT,                    D_,  QR_);
    transw(stream, kv_a_w, wqakvT + (size_t)QR_ * D_, D_,  KVR_+ROPE_);
    transw(stream, q_b_w,  wqbT,  QR_, H_*QKD_);
    transw(stream, kv_b_w, wkvbT, KVR_, H_*(NOPE_+VD_));
    transw(stream, o_w,    woT,   H_*VD_, D_);
    transw(stream, ffn_w1, wf1T,  D_,  4*D_);
    transw(stream, ffn_w2, wf2T,  4*D_, D_);

    // ---- pre-attention pipeline ----
    rmsnorm_k<<<S_, 256, 0, stream>>>(x, norm1_w, hs, D_, D_, D_);

    // fused qa+kva: 256^2 GEMM split-K 3 -> fused reduce+dual-rmsnorm+pe
    gemm256(stream, hs, wqakvT, qakvaP, nullptr, S_, QKVN, D_, D_, D_, QKVN,
            (long long)S_*QKVN, 6, 3, 768);
    red_qakva_k<<<S_, 256, 0, stream>>>(qakvaP, q_a_ln_w, kv_a_ln_w, qln, kvln, pe);

    // q_b GEMM split-K 2 -> fused reduce+build_q
    gemm256(stream, qln, wqbT, qbP, nullptr, S_, H_*QKD_, QR_, QR_, QR_, H_*QKD_,
            (long long)S_*(H_*QKD_), 6, 2, 768);
    red_buildq_k<<<S_, 256, 0, stream>>>(qbP, qf);

    gemm(stream, kvln, wkvbT, kvb, nullptr, nullptr, S_, H_*(NOPE_+VD_), KVR_,
         KVR_, KVR_, H_*(NOPE_+VD_), 0, 0, 0, 1, 1, 0);

    build_k<<<dim3(S_, H_), 192, 0, stream>>>(kvb, pe, kf);
    transpose_v<<<dim3(VD_/32, S_/32, H_), dim3(32, 8), 0, stream>>>(kvb, vT);

    // ---- attention: 2 groups of 8 heads; PV split-K 4 with partials ----
    for (int g = 0; g < 2; ++g) {
        const bf16* qfg = qf + (size_t)g * 8 * S_ * QKD_;
        const bf16* kfg = kf + (size_t)g * 8 * S_ * QKD_;
        const bf16* vTg = vT + (size_t)g * 8 * VD_ * S_;
        gemm(stream, qfg, kfg, Sc, nullptr, nullptr,
             S_, S_, QKD_, QKD_, QKD_, S_,
             (long long)S_*QKD_, (long long)S_*QKD_, (long long)S_*S_, 8, 1, 1);
        softmax_k<<<dim3(S_, 8), 256, 0, stream>>>(Sc);
        gemm(stream, Sc, vTg, pvP, nullptr, nullptr,
             S_, VD_, S_, S_, S_, VD_,
             (long long)S_*S_, (long long)VD_*S_, (long long)S_*VD_, 8, 6, 2, 4, 512);
        pv_red<<<dim3(S_, 8), 32, 0, stream>>>(pvP, ao, g);
    }

    // ---- o-projection: 256^2 split-K 4 -> fused reduce+residual+rmsnorm ----
    gemm256(stream, ao, woT, oP, nullptr, S_, D_, H_*VD_, H_*VD_, H_*VD_, D_,
            (long long)S_*D_, 6, 4, 512);
    red_o_rms_k<<<S_, 256, 0, stream>>>(oP, x, norm2_w, x2, h2);

    // ---- FFN ----
    gemm256(stream, h2, wf1T, a1, ffn_b1, S_, 4*D_, D_, D_, D_, 4*D_,
            0, 3, 1, 0);
    gemm256(stream, a1, wf2T, f2P, nullptr, S_, D_, 4*D_, 4*D_, 4*D_, D_,
            (long long)S_*D_, 6, 4, 2048);
    red_k<<<1024, 256, 0, stream>>>(f2P, (long long)S_*D_/4, 4, x2, ffn_b2, D_/4,
                                    out, nullptr, (long long)S_*D_/4);
}